// Round 1
// 1442.049 us; speedup vs baseline: 1.1315x; 1.1315x over previous
//
#include <hip/hip_runtime.h>

typedef __attribute__((ext_vector_type(8))) short bf16x8;
typedef __attribute__((ext_vector_type(4))) float f32x4;

#define D_EMB 2048
#define NQ    256
#define NB    4
#define NS    2048
#define NH    16
#define HK    128
#define FF    8192

__device__ __forceinline__ float b2f(short s) {
  union { unsigned int u; float f; } c;
  c.u = ((unsigned int)(unsigned short)s) << 16;
  return c.f;
}
__device__ __forceinline__ short f2b(float f) {
  union { float f; unsigned int u; } c; c.f = f;
  unsigned int u = c.u;
  u += 0x7FFFu + ((u >> 16) & 1u);   // RNE
  return (short)(u >> 16);
}
__device__ __forceinline__ void gload_lds16(const short* g, short* l) {
  __builtin_amdgcn_global_load_lds(
      (const __attribute__((address_space(1))) void*)g,
      (__attribute__((address_space(3))) void*)l, 16, 0, 0);
}

// ---------------- elementwise fp32 -> bf16 ----------------
__global__ __launch_bounds__(256)
void cvt_kernel(const float* __restrict__ in, short* __restrict__ out, int n8) {
  const int i = (blockIdx.x * 256 + threadIdx.x) * 8;
  if (i >= n8) return;
  f32x4 a = *(const f32x4*)(in + i), b = *(const f32x4*)(in + i + 4);
  bf16x8 t;
#pragma unroll
  for (int j = 0; j < 4; ++j) { t[j] = f2b(a[j]); t[4 + j] = f2b(b[j]); }
  *(bf16x8*)(out + i) = t;
}

// ---------------- W[Kd,N] fp32 -> Wt[N,Kd] bf16 (64x64 tiles) ----------------
__global__ __launch_bounds__(256)
void transpose_kernel(const float* __restrict__ W, short* __restrict__ Wt,
                      int Kd, int N) {
  __shared__ short tile[64][65];   // [n][k]
  const int k0 = blockIdx.y * 64, n0 = blockIdx.x * 64;
  const int tid = threadIdx.x;
  const int r = tid >> 2, c4 = (tid & 3) * 16;
#pragma unroll
  for (int i = 0; i < 16; i += 4) {
    f32x4 v = *(const f32x4*)(W + (size_t)(k0 + r) * N + n0 + c4 + i);
#pragma unroll
    for (int j = 0; j < 4; ++j) tile[c4 + i + j][r] = f2b(v[j]);
  }
  __syncthreads();
  bf16x8 o0, o1;
#pragma unroll
  for (int j = 0; j < 8; ++j) { o0[j] = tile[r][c4 + j]; o1[j] = tile[r][c4 + 8 + j]; }
  short* dst = Wt + (size_t)(n0 + r) * Kd + k0 + c4;
  *(bf16x8*)dst = o0;
  *(bf16x8*)(dst + 8) = o1;
}

// ---------------- LayerNorm (row = 2048), fp32 in -> bf16 out ----------------
__global__ __launch_bounds__(256)
void ln_kernel(const float* __restrict__ x, const float* __restrict__ scale,
               const float* __restrict__ offset, short* __restrict__ out) {
  const int row = blockIdx.x, tid = threadIdx.x;
  const float* xr = x + (size_t)row * D_EMB + tid * 8;
  f32x4 v0 = *(const f32x4*)xr;
  f32x4 v1 = *(const f32x4*)(xr + 4);
  float f[8], s = 0.f, sq = 0.f;
#pragma unroll
  for (int i = 0; i < 4; ++i) { f[i] = v0[i]; f[4 + i] = v1[i]; }
#pragma unroll
  for (int i = 0; i < 8; ++i) { s += f[i]; sq += f[i] * f[i]; }
#pragma unroll
  for (int off = 1; off < 64; off <<= 1) {
    s  += __shfl_xor(s, off, 64);
    sq += __shfl_xor(sq, off, 64);
  }
  __shared__ float red[2][4];
  const int w = tid >> 6;
  if ((tid & 63) == 0) { red[0][w] = s; red[1][w] = sq; }
  __syncthreads();
  s  = red[0][0] + red[0][1] + red[0][2] + red[0][3];
  sq = red[1][0] + red[1][1] + red[1][2] + red[1][3];
  const float mu  = s * (1.f / D_EMB);
  const float var = sq * (1.f / D_EMB) - mu * mu;
  const float inv = rsqrtf(var + 1e-5f);
  bf16x8 ov;
#pragma unroll
  for (int i = 0; i < 8; ++i) {
    const int c = tid * 8 + i;
    ov[i] = f2b((f[i] - mu) * inv * scale[c] + offset[c]);
  }
  *(bf16x8*)(out + (size_t)row * D_EMB + tid * 8) = ov;
}

// ---------------- GEMM (m97 style): C = A[M,Kd] @ Wt[N,Kd]^T + bias ----------------
template<int EPI, int OUTF>
__global__ __launch_bounds__(256)
void gemm_kernel(const short* __restrict__ A, const short* __restrict__ Bt,
                 const float* __restrict__ bias, const float* __restrict__ res,
                 void* __restrict__ Cp, int M, int N, int Kd) {
  __shared__ short ldsA[128 * 32];
  __shared__ short ldsB[128 * 32];
  const int tid = threadIdx.x;
  const int m0 = blockIdx.y * 128, n0 = blockIdx.x * 128;
  const int w = tid >> 6, lane = tid & 63, l15 = lane & 15, quad = lane >> 4;
  const int wr = (w >> 1) * 64, wc = (w & 1) * 64;
  const int sr = tid >> 2;
  const int sc = (tid & 3) * 8;
  f32x4 acc[4][4];
#pragma unroll
  for (int mi = 0; mi < 4; ++mi)
#pragma unroll
    for (int ni = 0; ni < 4; ++ni) acc[mi][ni] = (f32x4){0.f, 0.f, 0.f, 0.f};

  const short* pa0 = A  + (size_t)(m0 + sr) * Kd + sc;
  const short* pa1 = A  + (size_t)(m0 + 64 + sr) * Kd + sc;
  const short* pb0 = Bt + (size_t)(n0 + sr) * Kd + sc;
  const short* pb1 = Bt + (size_t)(n0 + 64 + sr) * Kd + sc;

  for (int k0 = 0; k0 < Kd; k0 += 32) {
    __syncthreads();
    gload_lds16(pa0 + k0, ldsA + tid * 8);
    gload_lds16(pa1 + k0, ldsA + 2048 + tid * 8);
    gload_lds16(pb0 + k0, ldsB + tid * 8);
    gload_lds16(pb1 + k0, ldsB + 2048 + tid * 8);
    __syncthreads();
    bf16x8 af[4], bfr[4];
#pragma unroll
    for (int mi = 0; mi < 4; ++mi)
      af[mi] = *(bf16x8*)&ldsA[(wr + mi * 16 + l15) * 32 + quad * 8];
#pragma unroll
    for (int ni = 0; ni < 4; ++ni)
      bfr[ni] = *(bf16x8*)&ldsB[(wc + ni * 16 + l15) * 32 + quad * 8];
#pragma unroll
    for (int mi = 0; mi < 4; ++mi)
#pragma unroll
      for (int ni = 0; ni < 4; ++ni)
        acc[mi][ni] = __builtin_amdgcn_mfma_f32_16x16x32_bf16(
            af[mi], bfr[ni], acc[mi][ni], 0, 0, 0);
  }

#pragma unroll
  for (int mi = 0; mi < 4; ++mi) {
#pragma unroll
    for (int ni = 0; ni < 4; ++ni) {
      const int gn = n0 + wc + ni * 16 + l15;
      const float bv = bias[gn];
#pragma unroll
      for (int r = 0; r < 4; ++r) {
        const int gm = m0 + wr + mi * 16 + quad * 4 + r;
        float v = acc[mi][ni][r] + bv;
        if (EPI == 1) v += res[(size_t)gm * N + gn];
        if (EPI == 2) v = 0.5f * v * (1.f + erff(v * 0.70710678118654752f));
        if (OUTF) ((float*)Cp)[(size_t)gm * N + gn] = v;
        else      ((short*)Cp)[(size_t)gm * N + gn] = f2b(v);
      }
    }
  }
}

// ---------------- Flash cross-attention, 4-way KV split (partials) ----------------
// grid = 1024: XCD-grouped so the 16 blocks sharing one (b,h) land on one XCD.
// Each block: 64 q-rows x 512 kv positions -> unnormalized o + (m,l) partials.
__global__ __launch_bounds__(256)
void attn_part_kernel(const short* __restrict__ qh, const short* __restrict__ kh,
                      const short* __restrict__ vh, float* __restrict__ po,
                      float* __restrict__ pml) {
  const int bx = blockIdx.x;
  const int work = (bx & 7) * 128 + (bx >> 3);   // XCD-contiguous work id
  const int bh = work >> 4, sub = work & 15;
  const int qt = sub >> 2, split = sub & 3;
  const int b = bh >> 4, h = bh & 15;
  const int tid = threadIdx.x, w = tid >> 6, lane = tid & 63;
  const int l15 = lane & 15, quad = lane >> 4;
  const int q0 = qt * 64 + w * 16;

  __shared__ short ldsK[32 * 128];   // [t][d], XOR-swizzled by (t&7)<<4 bytes
  __shared__ short ldsV[128 * 32];   // [d][t], XOR-swizzled by ((d>>3)&3)<<4 bytes
  __shared__ short ldsP[4 * 16 * 32];// per-wave [q][t], XOR-swizzled by ((q>>1)&3)<<4

  const float sc = 0.08838834764831845f;

  bf16x8 aq[4];
  {
    const short* qrow = qh + ((size_t)(b * 256 + q0 + l15)) * D_EMB + h * 128;
#pragma unroll
    for (int s = 0; s < 4; ++s)
      aq[s] = *(const bf16x8*)(qrow + s * 32 + quad * 8);
  }

  f32x4 o[8];
  float m_run[4], l_run[4];
#pragma unroll
  for (int dt = 0; dt < 8; ++dt) o[dt] = (f32x4){0.f, 0.f, 0.f, 0.f};
#pragma unroll
  for (int r = 0; r < 4; ++r) { m_run[r] = -INFINITY; l_run[r] = 0.f; }

  // staging decode (constant over the loop)
  const int srow = tid >> 4;                 // 0..15 (second chunk = +16)
  const int j = tid & 15;
  const int ksw = (j ^ (srow & 7)) * 8;      // pre-swizzled global d-offset (shorts)
  const int t_beg = split * 512;

  for (int t0 = t_beg; t0 < t_beg + 512; t0 += 32) {
    __syncthreads();
    const size_t kb0 = ((size_t)(b * NS + t0 + srow)) * D_EMB + h * 128;
    const size_t kb1 = kb0 + (size_t)16 * D_EMB;
    // K: global_load_lds, linear LDS dest + pre-swizzled global source
    gload_lds16(kh + kb0 + ksw, ldsK + tid * 8);
    gload_lds16(kh + kb1 + ksw, ldsK + 2048 + tid * 8);
    // V: reg-staged transpose into swizzled [d][t]
    {
      bf16x8 v0 = *(const bf16x8*)(vh + kb0 + j * 8);
      bf16x8 v1 = *(const bf16x8*)(vh + kb1 + j * 8);
#pragma unroll
      for (int i = 0; i < 8; ++i) {
        const int d = j * 8 + i;
        const int swz = ((d >> 3) & 3) << 4;
        char* base = (char*)ldsV + (d << 6);
        *(short*)(base + ((srow << 1) ^ swz))        = v0[i];
        *(short*)(base + (((srow + 16) << 1) ^ swz)) = v1[i];
      }
    }
    __syncthreads();

    // QK^T
    f32x4 s0 = (f32x4){0.f, 0.f, 0.f, 0.f}, s1 = (f32x4){0.f, 0.f, 0.f, 0.f};
    const int kswr = (l15 & 7) << 4;
#pragma unroll
    for (int s = 0; s < 4; ++s) {
      const int cb = s * 64 + quad * 16;
      bf16x8 k0f = *(bf16x8*)((char*)ldsK + (l15 << 8)        + (cb ^ kswr));
      bf16x8 k1f = *(bf16x8*)((char*)ldsK + ((16 + l15) << 8) + (cb ^ kswr));
      s0 = __builtin_amdgcn_mfma_f32_16x16x32_bf16(aq[s], k0f, s0, 0, 0, 0);
      s1 = __builtin_amdgcn_mfma_f32_16x16x32_bf16(aq[s], k1f, s1, 0, 0, 0);
    }

    // online softmax (per q-row, 16-lane groups)
    float alpha_r[4];
#pragma unroll
    for (int r = 0; r < 4; ++r) {
      const float v0 = s0[r] * sc, v1 = s1[r] * sc;
      float mx = fmaxf(v0, v1);
#pragma unroll
      for (int off = 1; off < 16; off <<= 1) mx = fmaxf(mx, __shfl_xor(mx, off, 16));
      const float m_new = fmaxf(m_run[r], mx);
      const float p0 = expf(v0 - m_new), p1 = expf(v1 - m_new);
      float rs = p0 + p1;
#pragma unroll
      for (int off = 1; off < 16; off <<= 1) rs += __shfl_xor(rs, off, 16);
      alpha_r[r] = expf(m_run[r] - m_new);
      l_run[r] = l_run[r] * alpha_r[r] + rs;
      m_run[r] = m_new;
      const int prow = quad * 4 + r;
      const int psw = ((prow >> 1) & 3) << 4;
      char* pb = (char*)ldsP + w * 1024 + (prow << 6);
      *(short*)(pb + ((l15 << 1) ^ psw))        = f2b(p0);
      *(short*)(pb + (((16 + l15) << 1) ^ psw)) = f2b(p1);
    }
#pragma unroll
    for (int dt = 0; dt < 8; ++dt)
#pragma unroll
      for (int r = 0; r < 4; ++r) o[dt][r] *= alpha_r[r];

    // PV (ldsP is per-wave: no barrier needed, lgkmcnt orders within wave)
    bf16x8 pf = *(bf16x8*)((char*)ldsP + w * 1024 + (l15 << 6) +
                           ((quad << 4) ^ (((l15 >> 1) & 3) << 4)));
#pragma unroll
    for (int dt = 0; dt < 8; ++dt) {
      const int drow = dt * 16 + l15;
      bf16x8 vf = *(bf16x8*)((char*)ldsV + (drow << 6) +
                             ((quad << 4) ^ (((drow >> 3) & 3) << 4)));
      o[dt] = __builtin_amdgcn_mfma_f32_16x16x32_bf16(pf, vf, o[dt], 0, 0, 0);
    }
  }

  // write partials: po[(orow*4+split)*128 + d], pml[(orow*4+split)*2 + {0,1}]
  const int orow_base = (bh * 4 + qt) * 64 + w * 16;
#pragma unroll
  for (int dt = 0; dt < 8; ++dt)
#pragma unroll
    for (int r = 0; r < 4; ++r) {
      const size_t orow = (size_t)(orow_base + quad * 4 + r);
      po[(orow * 4 + split) * 128 + dt * 16 + l15] = o[dt][r];
    }
  if (l15 == 0) {
#pragma unroll
    for (int r = 0; r < 4; ++r) {
      const size_t orow = (size_t)(orow_base + quad * 4 + r);
      pml[(orow * 4 + split) * 2]     = m_run[r];
      pml[(orow * 4 + split) * 2 + 1] = l_run[r];
    }
  }
}

// ---------------- combine partials + learned bias kv position ----------------
// one wave per (b,h,q-row); grid = 16384/4 = 4096 blocks
__global__ __launch_bounds__(256)
void attn_combine_kernel(const short* __restrict__ qh, const float* __restrict__ bias_k,
                         const float* __restrict__ bias_v, const float* __restrict__ po,
                         const float* __restrict__ pml, short* __restrict__ ctx) {
  const int tid = threadIdx.x, w = tid >> 6, lane = tid & 63;
  const int task = blockIdx.x * 4 + w;            // 0..16383
  const int bh = task >> 8, qr = task & 255;
  const int b = bh >> 4, h = bh & 15;
  const int d0 = lane * 2;
  const float sc = 0.08838834764831845f;

  // bias-position logit: q . bias_k (128-dim dot across 64 lanes)
  const short* qrow = qh + ((size_t)(b * 256 + qr)) * D_EMB + h * 128 + d0;
  const unsigned int qv = *(const unsigned int*)qrow;
  const float q0 = b2f((short)(qv & 0xffffu));
  const float q1 = b2f((short)(qv >> 16));
  const float2 bk = *(const float2*)(bias_k + h * 128 + d0);
  float le = q0 * bk.x + q1 * bk.y;
#pragma unroll
  for (int off = 1; off < 64; off <<= 1) le += __shfl_xor(le, off, 64);
  le *= sc;

  const float* pm = pml + (size_t)task * 8;
  float m[4], l[4];
#pragma unroll
  for (int s = 0; s < 4; ++s) { m[s] = pm[s * 2]; l[s] = pm[s * 2 + 1]; }
  float mt = le;
#pragma unroll
  for (int s = 0; s < 4; ++s) mt = fmaxf(mt, m[s]);

  const float pe = expf(le - mt);
  const float2 bv = *(const float2*)(bias_v + h * 128 + d0);
  float acc0 = pe * bv.x, acc1 = pe * bv.y;
  float lt = pe;
#pragma unroll
  for (int s = 0; s < 4; ++s) {
    const float es = expf(m[s] - mt);
    lt += l[s] * es;
    const float2 op = *(const float2*)(po + ((size_t)task * 4 + s) * 128 + d0);
    acc0 += es * op.x;
    acc1 += es * op.y;
  }
  const float inv = 1.f / lt;
  const unsigned int pack =
      ((unsigned int)(unsigned short)f2b(acc1 * inv) << 16) |
      (unsigned short)f2b(acc0 * inv);
  *(unsigned int*)(ctx + ((size_t)(b * 256 + qr)) * D_EMB + h * 128 + d0) = pack;
}

extern "C" void kernel_launch(void* const* d_in, const int* in_sizes, int n_in,
                              void* d_out, int out_size, void* d_ws, size_t ws_size,
                              hipStream_t stream) {
  const float* x   = (const float*)d_in[0];
  const float* xf1 = (const float*)d_in[1];
  const float* xf2 = (const float*)d_in[2];
  const float* L1[12]; const float* L2[12];
  for (int j = 0; j < 12; ++j) { L1[j] = (const float*)d_in[3 + j]; L2[j] = (const float*)d_in[15 + j]; }
  const float* ln_mlp_s = (const float*)d_in[27];
  const float* ln_mlp_o = (const float*)d_in[28];
  const float* w_fc1    = (const float*)d_in[29];
  const float* b_fc1    = (const float*)d_in[30];
  const float* w_fc2    = (const float*)d_in[31];
  const float* b_fc2    = (const float*)d_in[32];
  float* out = (float*)d_out;

  const size_t SZ_XQ  = (size_t)NB * NQ * D_EMB;   // 2M elems
  const size_t SZ_KV  = (size_t)NB * NS * D_EMB;   // 16.8M elems
  const size_t SZ_W   = (size_t)FF * D_EMB;        // 16.8M elems (max weight)

  float* x1   = (float*)d_ws;
  float* x2   = x1 + SZ_XQ;
  short* h_ln = (short*)(x2 + SZ_XQ);
  short* qh   = h_ln + SZ_XQ;
  short* ctxb = qh + SZ_XQ;
  short* kh   = ctxb + SZ_XQ;
  short* vh   = kh + SZ_KV;
  short* xfb  = vh + SZ_KV;
  short* Wt   = xfb + SZ_KV;
  short* fc1b = kh;                    // alias: kh dead by MLP time
  // attention partials alias dead buffers during the attention phase:
  float* po   = (float*)Wt;            // 33.55 MB == SZ_W shorts, Wt dead (wv^T consumed)
  float* pml  = (float*)h_ln;          // 512 KB <= h_ln, h_ln dead (q-proj consumed)

  const dim3 blk(256);
  const dim3 g_q(D_EMB / 128, (NB * NQ) / 128);    // (16, 8)
  const dim3 g_kv(D_EMB / 128, (NB * NS) / 128);   // (16, 64)
  const dim3 g_f1(FF / 128, (NB * NQ) / 128);      // (64, 8)
  const dim3 g_tw(D_EMB / 64, D_EMB / 64);         // 2048x2048 transpose
  const dim3 g_tf1(FF / 64, D_EMB / 64);           // W[2048,8192]
  const dim3 g_tf2(D_EMB / 64, FF / 64);           // W[8192,2048]
  const int  g_cvt = (int)(SZ_KV / 8 / 256);

  // ---- layer 1 ----
  cvt_kernel<<<g_cvt, blk, 0, stream>>>(xf1, xfb, (int)SZ_KV);
  ln_kernel<<<NB * NQ, blk, 0, stream>>>(x, L1[0], L1[1], h_ln);
  transpose_kernel<<<g_tw, blk, 0, stream>>>(L1[2], Wt, D_EMB, D_EMB);
  gemm_kernel<0,0><<<g_q,  blk, 0, stream>>>(h_ln, Wt, L1[3], nullptr, qh, NB * NQ, D_EMB, D_EMB);
  transpose_kernel<<<g_tw, blk, 0, stream>>>(L1[4], Wt, D_EMB, D_EMB);
  gemm_kernel<0,0><<<g_kv, blk, 0, stream>>>(xfb, Wt, L1[5], nullptr, kh, NB * NS, D_EMB, D_EMB);
  transpose_kernel<<<g_tw, blk, 0, stream>>>(L1[6], Wt, D_EMB, D_EMB);
  gemm_kernel<0,0><<<g_kv, blk, 0, stream>>>(xfb, Wt, L1[7], nullptr, vh, NB * NS, D_EMB, D_EMB);
  attn_part_kernel<<<1024, blk, 0, stream>>>(qh, kh, vh, po, pml);
  attn_combine_kernel<<<4096, blk, 0, stream>>>(qh, L1[10], L1[11], po, pml, ctxb);
  transpose_kernel<<<g_tw, blk, 0, stream>>>(L1[8], Wt, D_EMB, D_EMB);
  gemm_kernel<1,1><<<g_q,  blk, 0, stream>>>(ctxb, Wt, L1[9], x, x1, NB * NQ, D_EMB, D_EMB);

  // ---- layer 2 ----
  cvt_kernel<<<g_cvt, blk, 0, stream>>>(xf2, xfb, (int)SZ_KV);
  ln_kernel<<<NB * NQ, blk, 0, stream>>>(x1, L2[0], L2[1], h_ln);
  transpose_kernel<<<g_tw, blk, 0, stream>>>(L2[2], Wt, D_EMB, D_EMB);
  gemm_kernel<0,0><<<g_q,  blk, 0, stream>>>(h_ln, Wt, L2[3], nullptr, qh, NB * NQ, D_EMB, D_EMB);
  transpose_kernel<<<g_tw, blk, 0, stream>>>(L2[4], Wt, D_EMB, D_EMB);
  gemm_kernel<0,0><<<g_kv, blk, 0, stream>>>(xfb, Wt, L2[5], nullptr, kh, NB * NS, D_EMB, D_EMB);
  transpose_kernel<<<g_tw, blk, 0, stream>>>(L2[6], Wt, D_EMB, D_EMB);
  gemm_kernel<0,0><<<g_kv, blk, 0, stream>>>(xfb, Wt, L2[7], nullptr, vh, NB * NS, D_EMB, D_EMB);
  attn_part_kernel<<<1024, blk, 0, stream>>>(qh, kh, vh, po, pml);
  attn_combine_kernel<<<4096, blk, 0, stream>>>(qh, L2[10], L2[11], po, pml, ctxb);
  transpose_kernel<<<g_tw, blk, 0, stream>>>(L2[8], Wt, D_EMB, D_EMB);
  gemm_kernel<1,1><<<g_q,  blk, 0, stream>>>(ctxb, Wt, L2[9], x1, x2, NB * NQ, D_EMB, D_EMB);

  // ---- MLP ----
  ln_kernel<<<NB * NQ, blk, 0, stream>>>(x2, ln_mlp_s, ln_mlp_o, h_ln);
  transpose_kernel<<<g_tf1, blk, 0, stream>>>(w_fc1, Wt, D_EMB, FF);
  gemm_kernel<2,0><<<g_f1, blk, 0, stream>>>(h_ln, Wt, b_fc1, nullptr, fc1b, NB * NQ, FF, D_EMB);
  transpose_kernel<<<g_tf2, blk, 0, stream>>>(w_fc2, Wt, FF, D_EMB);
  gemm_kernel<1,1><<<g_q,  blk, 0, stream>>>(fc1b, Wt, b_fc2, x2, out, NB * NQ, D_EMB, FF);
}

// Round 3
// 1298.564 us; speedup vs baseline: 1.2566x; 1.1105x over previous
//
#include <hip/hip_runtime.h>

typedef __attribute__((ext_vector_type(8))) short bf16x8;
typedef __attribute__((ext_vector_type(4))) float f32x4;

#define D_EMB 2048
#define NQ    256
#define NB    4
#define NS    2048
#define NH    16
#define HK    128
#define FF    8192

__device__ __forceinline__ float b2f(short s) {
  union { unsigned int u; float f; } c;
  c.u = ((unsigned int)(unsigned short)s) << 16;
  return c.f;
}
__device__ __forceinline__ short f2b(float f) {
  union { float f; unsigned int u; } c; c.f = f;
  unsigned int u = c.u;
  u += 0x7FFFu + ((u >> 16) & 1u);   // RNE
  return (short)(u >> 16);
}
__device__ __forceinline__ void gload_lds16(const short* g, short* l) {
  __builtin_amdgcn_global_load_lds(
      (const __attribute__((address_space(1))) void*)g,
      (__attribute__((address_space(3))) void*)l, 16, 0, 0);
}

// ---------------- elementwise fp32 -> bf16 ----------------
__global__ __launch_bounds__(256)
void cvt_kernel(const float* __restrict__ in, short* __restrict__ out, int n8) {
  const int i = (blockIdx.x * 256 + threadIdx.x) * 8;
  if (i >= n8) return;
  f32x4 a = *(const f32x4*)(in + i), b = *(const f32x4*)(in + i + 4);
  bf16x8 t;
#pragma unroll
  for (int j = 0; j < 4; ++j) { t[j] = f2b(a[j]); t[4 + j] = f2b(b[j]); }
  *(bf16x8*)(out + i) = t;
}

// ---------------- W[Kd,N] fp32 -> Wt[N,Kd] bf16 (64x64 tiles) ----------------
__global__ __launch_bounds__(256)
void transpose_kernel(const float* __restrict__ W, short* __restrict__ Wt,
                      int Kd, int N) {
  __shared__ short tile[64][65];   // [n][k]
  const int k0 = blockIdx.y * 64, n0 = blockIdx.x * 64;
  const int tid = threadIdx.x;
  const int r = tid >> 2, c4 = (tid & 3) * 16;
#pragma unroll
  for (int i = 0; i < 16; i += 4) {
    f32x4 v = *(const f32x4*)(W + (size_t)(k0 + r) * N + n0 + c4 + i);
#pragma unroll
    for (int j = 0; j < 4; ++j) tile[c4 + i + j][r] = f2b(v[j]);
  }
  __syncthreads();
  bf16x8 o0, o1;
#pragma unroll
  for (int j = 0; j < 8; ++j) { o0[j] = tile[r][c4 + j]; o1[j] = tile[r][c4 + 8 + j]; }
  short* dst = Wt + (size_t)(n0 + r) * Kd + k0 + c4;
  *(bf16x8*)dst = o0;
  *(bf16x8*)(dst + 8) = o1;
}

// ---------------- LayerNorm (row = 2048), fp32 in -> bf16 out ----------------
__global__ __launch_bounds__(256)
void ln_kernel(const float* __restrict__ x, const float* __restrict__ scale,
               const float* __restrict__ offset, short* __restrict__ out) {
  const int row = blockIdx.x, tid = threadIdx.x;
  const float* xr = x + (size_t)row * D_EMB + tid * 8;
  f32x4 v0 = *(const f32x4*)xr;
  f32x4 v1 = *(const f32x4*)(xr + 4);
  float f[8], s = 0.f, sq = 0.f;
#pragma unroll
  for (int i = 0; i < 4; ++i) { f[i] = v0[i]; f[4 + i] = v1[i]; }
#pragma unroll
  for (int i = 0; i < 8; ++i) { s += f[i]; sq += f[i] * f[i]; }
#pragma unroll
  for (int off = 1; off < 64; off <<= 1) {
    s  += __shfl_xor(s, off, 64);
    sq += __shfl_xor(sq, off, 64);
  }
  __shared__ float red[2][4];
  const int w = tid >> 6;
  if ((tid & 63) == 0) { red[0][w] = s; red[1][w] = sq; }
  __syncthreads();
  s  = red[0][0] + red[0][1] + red[0][2] + red[0][3];
  sq = red[1][0] + red[1][1] + red[1][2] + red[1][3];
  const float mu  = s * (1.f / D_EMB);
  const float var = sq * (1.f / D_EMB) - mu * mu;
  const float inv = rsqrtf(var + 1e-5f);
  bf16x8 ov;
#pragma unroll
  for (int i = 0; i < 8; ++i) {
    const int c = tid * 8 + i;
    ov[i] = f2b((f[i] - mu) * inv * scale[c] + offset[c]);
  }
  *(bf16x8*)(out + (size_t)row * D_EMB + tid * 8) = ov;
}

// ---------------- GEMM 128x128 (m97 style): small-M shapes ----------------
template<int EPI, int OUTF>
__global__ __launch_bounds__(256)
void gemm_kernel(const short* __restrict__ A, const short* __restrict__ Bt,
                 const float* __restrict__ bias, const float* __restrict__ res,
                 void* __restrict__ Cp, int M, int N, int Kd) {
  __shared__ short ldsA[128 * 32];
  __shared__ short ldsB[128 * 32];
  const int tid = threadIdx.x;
  const int m0 = blockIdx.y * 128, n0 = blockIdx.x * 128;
  const int w = tid >> 6, lane = tid & 63, l15 = lane & 15, quad = lane >> 4;
  const int wr = (w >> 1) * 64, wc = (w & 1) * 64;
  const int sr = tid >> 2;
  const int sc = (tid & 3) * 8;
  f32x4 acc[4][4];
#pragma unroll
  for (int mi = 0; mi < 4; ++mi)
#pragma unroll
    for (int ni = 0; ni < 4; ++ni) acc[mi][ni] = (f32x4){0.f, 0.f, 0.f, 0.f};

  const short* pa0 = A  + (size_t)(m0 + sr) * Kd + sc;
  const short* pa1 = A  + (size_t)(m0 + 64 + sr) * Kd + sc;
  const short* pb0 = Bt + (size_t)(n0 + sr) * Kd + sc;
  const short* pb1 = Bt + (size_t)(n0 + 64 + sr) * Kd + sc;

  for (int k0 = 0; k0 < Kd; k0 += 32) {
    __syncthreads();
    gload_lds16(pa0 + k0, ldsA + tid * 8);
    gload_lds16(pa1 + k0, ldsA + 2048 + tid * 8);
    gload_lds16(pb0 + k0, ldsB + tid * 8);
    gload_lds16(pb1 + k0, ldsB + 2048 + tid * 8);
    __syncthreads();
    bf16x8 af[4], bfr[4];
#pragma unroll
    for (int mi = 0; mi < 4; ++mi)
      af[mi] = *(bf16x8*)&ldsA[(wr + mi * 16 + l15) * 32 + quad * 8];
#pragma unroll
    for (int ni = 0; ni < 4; ++ni)
      bfr[ni] = *(bf16x8*)&ldsB[(wc + ni * 16 + l15) * 32 + quad * 8];
#pragma unroll
    for (int mi = 0; mi < 4; ++mi)
#pragma unroll
      for (int ni = 0; ni < 4; ++ni)
        acc[mi][ni] = __builtin_amdgcn_mfma_f32_16x16x32_bf16(
            af[mi], bfr[ni], acc[mi][ni], 0, 0, 0);
  }

#pragma unroll
  for (int mi = 0; mi < 4; ++mi) {
#pragma unroll
    for (int ni = 0; ni < 4; ++ni) {
      const int gn = n0 + wc + ni * 16 + l15;
      const float bv = bias[gn];
#pragma unroll
      for (int r = 0; r < 4; ++r) {
        const int gm = m0 + wr + mi * 16 + quad * 4 + r;
        float v = acc[mi][ni][r] + bv;
        if (EPI == 1) v += res[(size_t)gm * N + gn];
        if (EPI == 2) v = 0.5f * v * (1.f + erff(v * 0.70710678118654752f));
        if (OUTF) ((float*)Cp)[(size_t)gm * N + gn] = v;
        else      ((short*)Cp)[(size_t)gm * N + gn] = f2b(v);
      }
    }
  }
}

// ---------------- GEMM 256x256, BK=64, 8-wave, 4-phase pipelined (T2+T3+T4+T5) --------
// C = A[M,Kd] @ Bt[N,Kd]^T + bias.  Requires M%256==0, N%256==0, Kd%128==0, grid%8==0.
// LDS layout per buffer (shorts): A-k0 [0,8192) A-k1 [8192,16384) B-k0 [16384,24576)
// B-k1 [24576,32768).  Within a 16KB half: elem (r, kc) at (r>>3)*256 + (kc>>3)*64 + (r&7)*8
// -> consecutive lanes of a frag read hit distinct 4-bank groups (conflict-free b128).
// Staging: linear global_load_lds dest, per-lane pre-permuted global source.
#define FENCE() asm volatile("" ::: "memory")

#define G_STAGE(DB2, DSTOFF, PS0, PS1, KON)                                     \
  gload_lds16((PS0) + (KON), sh + (DB2) * 32768 + (DSTOFF) + tid * 8);          \
  gload_lds16((PS1) + (KON), sh + (DB2) * 32768 + (DSTOFF) + 4096 + tid * 8);

#define PHASE(DB, MG, KH, DSTOFF, PS0, PS1, KON, DOVM)                          \
  {                                                                             \
    const short* _ra = sh + (DB) * 32768 + (KH) * 8192;                         \
    const short* _rb = sh + (DB) * 32768 + 16384 + (KH) * 8192;                 \
    if ((MG) == 0) {                                                            \
      bfrag[0] = *(const bf16x8*)(_rb + boff[0]);                               \
      bfrag[1] = *(const bf16x8*)(_rb + boff[1]);                               \
      bfrag[2] = *(const bf16x8*)(_rb + boff[2]);                               \
      bfrag[3] = *(const bf16x8*)(_rb + boff[3]);                               \
    }                                                                           \
    afrag[0] = *(const bf16x8*)(_ra + aoff[(MG) * 4 + 0]);                      \
    afrag[1] = *(const bf16x8*)(_ra + aoff[(MG) * 4 + 1]);                      \
    afrag[2] = *(const bf16x8*)(_ra + aoff[(MG) * 4 + 2]);                      \
    afrag[3] = *(const bf16x8*)(_ra + aoff[(MG) * 4 + 3]);                      \
    G_STAGE((DB) ^ 1, DSTOFF, PS0, PS1, KON)                                    \
    if (DOVM) asm volatile("s_waitcnt vmcnt(4)" ::: "memory");                  \
    __builtin_amdgcn_s_barrier();                                               \
    FENCE();                                                                    \
    __builtin_amdgcn_s_setprio(1);                                              \
    _Pragma("unroll")                                                           \
    for (int mf = 0; mf < 4; ++mf)                                              \
      _Pragma("unroll")                                                         \
      for (int nf = 0; nf < 4; ++nf)                                            \
        acc[(MG) * 4 + mf][nf] = __builtin_amdgcn_mfma_f32_16x16x32_bf16(       \
            afrag[mf], bfrag[nf], acc[(MG) * 4 + mf][nf], 0, 0, 0);             \
    __builtin_amdgcn_s_setprio(0);                                              \
    __builtin_amdgcn_s_barrier();                                               \
    FENCE();                                                                    \
  }

#define TILE(DB, KON)                                                           \
  PHASE(DB, 0, 0, 0,     pA0, pA1, (KON), 0)                                    \
  PHASE(DB, 1, 0, 16384, pB0, pB1, (KON), 1)                                    \
  PHASE(DB, 0, 1, 8192,  pA0, pA1, (KON) + 32, 0)                               \
  PHASE(DB, 1, 1, 24576, pB0, pB1, (KON) + 32, 1)

template<int EPI, int OUTF>
__global__ __launch_bounds__(512, 2)
void gemm256_kernel(const short* __restrict__ A, const short* __restrict__ Bt,
                    const float* __restrict__ bias, const float* __restrict__ res,
                    void* __restrict__ Cp, int M, int N, int Kd) {
  __shared__ short sh[65536];   // 128 KiB
  const int tid = threadIdx.x;
  const int w = tid >> 6, lane = tid & 63;
  const int l15 = lane & 15, quad = lane >> 4;
  const int wm = w >> 2, wn = w & 3;

  // XCD-chunked swizzle, m-major work id (each XCD owns contiguous m-rows)
  const int nTn = N >> 8;
  const int cpx = gridDim.x >> 3;
  const int wid = (blockIdx.x & 7) * cpx + (blockIdx.x >> 3);
  const int m0 = (wid / nTn) * 256, n0 = (wid % nTn) * 256;

  // staging decode: chunk c covers LDS bytes [c*16, c*16+16) of a 16KB half;
  // that LDS slot holds global elem (r, kb) with r=(c>>5)*8+(c&7), kb=(c>>3)&3.
  const int c0 = tid, c1 = 512 + tid;
  const int r0 = ((c0 >> 5) << 3) + (c0 & 7), kb0 = (c0 >> 3) & 3;
  const int r1 = ((c1 >> 5) << 3) + (c1 & 7), kb1 = (c1 >> 3) & 3;
  const short* pA0 = A  + (size_t)(m0 + r0) * Kd + kb0 * 8;
  const short* pA1 = A  + (size_t)(m0 + r1) * Kd + kb1 * 8;
  const short* pB0 = Bt + (size_t)(n0 + r0) * Kd + kb0 * 8;
  const short* pB1 = Bt + (size_t)(n0 + r1) * Kd + kb1 * 8;

  // per-thread fragment read offsets (shorts, within a 16KB half)
  int aoff[8], boff[4];
#pragma unroll
  for (int mf = 0; mf < 8; ++mf) {
    const int r = wm * 128 + mf * 16 + l15;
    aoff[mf] = ((r >> 3) << 8) + (quad << 6) + ((r & 7) << 3);
  }
#pragma unroll
  for (int nf = 0; nf < 4; ++nf) {
    const int r = wn * 64 + nf * 16 + l15;
    boff[nf] = ((r >> 3) << 8) + (quad << 6) + ((r & 7) << 3);
  }

  f32x4 acc[8][4];
#pragma unroll
  for (int mf = 0; mf < 8; ++mf)
#pragma unroll
    for (int nf = 0; nf < 4; ++nf) acc[mf][nf] = (f32x4){0.f, 0.f, 0.f, 0.f};
  bf16x8 afrag[4], bfrag[4];

  const int NT = Kd >> 6;   // K-tiles of 64

  // prologue: stage tile 0 into buf0 (issue order = consumption order)
  G_STAGE(0, 0,     pA0, pA1, 0)
  G_STAGE(0, 16384, pB0, pB1, 0)
  G_STAGE(0, 8192,  pA0, pA1, 32)
  G_STAGE(0, 24576, pB0, pB1, 32)
  asm volatile("s_waitcnt vmcnt(4)" ::: "memory");   // A-k0,B-k0 of tile 0 landed
  __builtin_amdgcn_s_barrier();
  FENCE();

  for (int kt = 0; kt < NT; kt += 2) {
    const int k1n = (kt + 1) * 64;                          // src col of tile kt+1
    const int k2n = (kt + 2 < NT) ? (kt + 2) * 64 : 0;      // wrap: re-stage tile 0 (unused)
    TILE(0, k1n)
    TILE(1, k2n)
  }
  // defensive drain before epilogue / block retire
  asm volatile("s_waitcnt vmcnt(0) lgkmcnt(0)" ::: "memory");

  // epilogue
#pragma unroll
  for (int mf = 0; mf < 8; ++mf) {
#pragma unroll
    for (int nf = 0; nf < 4; ++nf) {
      const int gn = n0 + wn * 64 + nf * 16 + l15;
      const float bv = bias[gn];
#pragma unroll
      for (int r = 0; r < 4; ++r) {
        const int gm = m0 + wm * 128 + mf * 16 + quad * 4 + r;
        float v = acc[mf][nf][r] + bv;
        if (EPI == 1) v += res[(size_t)gm * N + gn];
        if (EPI == 2) v = 0.5f * v * (1.f + erff(v * 0.70710678118654752f));
        if (OUTF) ((float*)Cp)[(size_t)gm * N + gn] = v;
        else      ((short*)Cp)[(size_t)gm * N + gn] = f2b(v);
      }
    }
  }
}

// ---------------- Flash cross-attention, 4-way KV split (partials) ----------------
__global__ __launch_bounds__(256)
void attn_part_kernel(const short* __restrict__ qh, const short* __restrict__ kh,
                      const short* __restrict__ vh, float* __restrict__ po,
                      float* __restrict__ pml) {
  const int bx = blockIdx.x;
  const int work = (bx & 7) * 128 + (bx >> 3);   // XCD-contiguous work id
  const int bh = work >> 4, sub = work & 15;
  const int qt = sub >> 2, split = sub & 3;
  const int b = bh >> 4, h = bh & 15;
  const int tid = threadIdx.x, w = tid >> 6, lane = tid & 63;
  const int l15 = lane & 15, quad = lane >> 4;
  const int q0 = qt * 64 + w * 16;

  __shared__ short ldsK[32 * 128];   // [t][d], XOR-swizzled by (t&7)<<4 bytes
  __shared__ short ldsV[128 * 32];   // [d][t], XOR-swizzled by ((d>>3)&3)<<4 bytes
  __shared__ short ldsP[4 * 16 * 32];// per-wave [q][t], XOR-swizzled by ((q>>1)&3)<<4

  const float sc = 0.08838834764831845f;

  bf16x8 aq[4];
  {
    const short* qrow = qh + ((size_t)(b * 256 + q0 + l15)) * D_EMB + h * 128;
#pragma unroll
    for (int s = 0; s < 4; ++s)
      aq[s] = *(const bf16x8*)(qrow + s * 32 + quad * 8);
  }

  f32x4 o[8];
  float m_run[4], l_run[4];
#pragma unroll
  for (int dt = 0; dt < 8; ++dt) o[dt] = (f32x4){0.f, 0.f, 0.f, 0.f};
#pragma unroll
  for (int r = 0; r < 4; ++r) { m_run[r] = -INFINITY; l_run[r] = 0.f; }

  const int srow = tid >> 4;
  const int j = tid & 15;
  const int ksw = (j ^ (srow & 7)) * 8;
  const int t_beg = split * 512;

  for (int t0 = t_beg; t0 < t_beg + 512; t0 += 32) {
    __syncthreads();
    const size_t kb0 = ((size_t)(b * NS + t0 + srow)) * D_EMB + h * 128;
    const size_t kb1 = kb0 + (size_t)16 * D_EMB;
    gload_lds16(kh + kb0 + ksw, ldsK + tid * 8);
    gload_lds16(kh + kb1 + ksw, ldsK + 2048 + tid * 8);
    {
      bf16x8 v0 = *(const bf16x8*)(vh + kb0 + j * 8);
      bf16x8 v1 = *(const bf16x8*)(vh + kb1 + j * 8);
#pragma unroll
      for (int i = 0; i < 8; ++i) {
        const int d = j * 8 + i;
        const int swz = ((d >> 3) & 3) << 4;
        char* base = (char*)ldsV + (d << 6);
        *(short*)(base + ((srow << 1) ^ swz))        = v0[i];
        *(short*)(base + (((srow + 16) << 1) ^ swz)) = v1[i];
      }
    }
    __syncthreads();

    f32x4 s0 = (f32x4){0.f, 0.f, 0.f, 0.f}, s1 = (f32x4){0.f, 0.f, 0.f, 0.f};
    const int kswr = (l15 & 7) << 4;
#pragma unroll
    for (int s = 0; s < 4; ++s) {
      const int cb = s * 64 + quad * 16;
      bf16x8 k0f = *(bf16x8*)((char*)ldsK + (l15 << 8)        + (cb ^ kswr));
      bf16x8 k1f = *(bf16x8*)((char*)ldsK + ((16 + l15) << 8) + (cb ^ kswr));
      s0 = __builtin_amdgcn_mfma_f32_16x16x32_bf16(aq[s], k0f, s0, 0, 0, 0);
      s1 = __builtin_amdgcn_mfma_f32_16x16x32_bf16(aq[s], k1f, s1, 0, 0, 0);
    }

    float alpha_r[4];
#pragma unroll
    for (int r = 0; r < 4; ++r) {
      const float v0 = s0[r] * sc, v1 = s1[r] * sc;
      float mx = fmaxf(v0, v1);
#pragma unroll
      for (int off = 1; off < 16; off <<= 1) mx = fmaxf(mx, __shfl_xor(mx, off, 16));
      const float m_new = fmaxf(m_run[r], mx);
      const float p0 = expf(v0 - m_new), p1 = expf(v1 - m_new);
      float rs = p0 + p1;
#pragma unroll
      for (int off = 1; off < 16; off <<= 1) rs += __shfl_xor(rs, off, 16);
      alpha_r[r] = expf(m_run[r] - m_new);
      l_run[r] = l_run[r] * alpha_r[r] + rs;
      m_run[r] = m_new;
      const int prow = quad * 4 + r;
      const int psw = ((prow >> 1) & 3) << 4;
      char* pb = (char*)ldsP + w * 1024 + (prow << 6);
      *(short*)(pb + ((l15 << 1) ^ psw))        = f2b(p0);
      *(short*)(pb + (((16 + l15) << 1) ^ psw)) = f2b(p1);
    }
#pragma unroll
    for (int dt = 0; dt < 8; ++dt)
#pragma unroll
      for (int r = 0; r < 4; ++r) o[dt][r] *= alpha_r[r];

    bf16x8 pf = *(bf16x8*)((char*)ldsP + w * 1024 + (l15 << 6) +
                           ((quad << 4) ^ (((l15 >> 1) & 3) << 4)));
#pragma unroll
    for (int dt = 0; dt < 8; ++dt) {
      const int drow = dt * 16 + l15;
      bf16x8 vf = *(bf16x8*)((char*)ldsV + (drow << 6) +
                             ((quad << 4) ^ (((drow >> 3) & 3) << 4)));
      o[dt] = __builtin_amdgcn_mfma_f32_16x16x32_bf16(pf, vf, o[dt], 0, 0, 0);
    }
  }

  const int orow_base = (bh * 4 + qt) * 64 + w * 16;
#pragma unroll
  for (int dt = 0; dt < 8; ++dt)
#pragma unroll
    for (int r = 0; r < 4; ++r) {
      const size_t orow = (size_t)(orow_base + quad * 4 + r);
      po[(orow * 4 + split) * 128 + dt * 16 + l15] = o[dt][r];
    }
  if (l15 == 0) {
#pragma unroll
    for (int r = 0; r < 4; ++r) {
      const size_t orow = (size_t)(orow_base + quad * 4 + r);
      pml[(orow * 4 + split) * 2]     = m_run[r];
      pml[(orow * 4 + split) * 2 + 1] = l_run[r];
    }
  }
}

// ---------------- combine partials + learned bias kv position ----------------
__global__ __launch_bounds__(256)
void attn_combine_kernel(const short* __restrict__ qh, const float* __restrict__ bias_k,
                         const float* __restrict__ bias_v, const float* __restrict__ po,
                         const float* __restrict__ pml, short* __restrict__ ctx) {
  const int tid = threadIdx.x, w = tid >> 6, lane = tid & 63;
  const int task = blockIdx.x * 4 + w;            // 0..16383
  const int bh = task >> 8, qr = task & 255;
  const int b = bh >> 4, h = bh & 15;
  const int d0 = lane * 2;
  const float sc = 0.08838834764831845f;

  const short* qrow = qh + ((size_t)(b * 256 + qr)) * D_EMB + h * 128 + d0;
  const unsigned int qv = *(const unsigned int*)qrow;
  const float q0 = b2f((short)(qv & 0xffffu));
  const float q1 = b2f((short)(qv >> 16));
  const float2 bk = *(const float2*)(bias_k + h * 128 + d0);
  float le = q0 * bk.x + q1 * bk.y;
#pragma unroll
  for (int off = 1; off < 64; off <<= 1) le += __shfl_xor(le, off, 64);
  le *= sc;

  const float* pm = pml + (size_t)task * 8;
  float m[4], l[4];
#pragma unroll
  for (int s = 0; s < 4; ++s) { m[s] = pm[s * 2]; l[s] = pm[s * 2 + 1]; }
  float mt = le;
#pragma unroll
  for (int s = 0; s < 4; ++s) mt = fmaxf(mt, m[s]);

  const float pe = expf(le - mt);
  const float2 bv = *(const float2*)(bias_v + h * 128 + d0);
  float acc0 = pe * bv.x, acc1 = pe * bv.y;
  float lt = pe;
#pragma unroll
  for (int s = 0; s < 4; ++s) {
    const float es = expf(m[s] - mt);
    lt += l[s] * es;
    const float2 op = *(const float2*)(po + ((size_t)task * 4 + s) * 128 + d0);
    acc0 += es * op.x;
    acc1 += es * op.y;
  }
  const float inv = 1.f / lt;
  const unsigned int pack =
      ((unsigned int)(unsigned short)f2b(acc1 * inv) << 16) |
      (unsigned short)f2b(acc0 * inv);
  *(unsigned int*)(ctx + ((size_t)(b * 256 + qr)) * D_EMB + h * 128 + d0) = pack;
}

extern "C" void kernel_launch(void* const* d_in, const int* in_sizes, int n_in,
                              void* d_out, int out_size, void* d_ws, size_t ws_size,
                              hipStream_t stream) {
  const float* x   = (const float*)d_in[0];
  const float* xf1 = (const float*)d_in[1];
  const float* xf2 = (const float*)d_in[2];
  const float* L1[12]; const float* L2[12];
  for (int j = 0; j < 12; ++j) { L1[j] = (const float*)d_in[3 + j]; L2[j] = (const float*)d_in[15 + j]; }
  const float* ln_mlp_s = (const float*)d_in[27];
  const float* ln_mlp_o = (const float*)d_in[28];
  const float* w_fc1    = (const float*)d_in[29];
  const float* b_fc1    = (const float*)d_in[30];
  const float* w_fc2    = (const float*)d_in[31];
  const float* b_fc2    = (const float*)d_in[32];
  float* out = (float*)d_out;

  const size_t SZ_XQ  = (size_t)NB * NQ * D_EMB;   // 2M elems
  const size_t SZ_KV  = (size_t)NB * NS * D_EMB;   // 16.8M elems
  const size_t SZ_W   = (size_t)FF * D_EMB;        // 16.8M elems (max weight)

  float* x1   = (float*)d_ws;
  float* x2   = x1 + SZ_XQ;
  short* h_ln = (short*)(x2 + SZ_XQ);
  short* qh   = h_ln + SZ_XQ;
  short* ctxb = qh + SZ_XQ;
  short* kh   = ctxb + SZ_XQ;
  short* vh   = kh + SZ_KV;
  short* xfb  = vh + SZ_KV;
  short* Wt   = xfb + SZ_KV;
  short* fc1b = kh;                    // alias: kh dead by MLP time
  float* po   = (float*)Wt;            // partials alias (Wt dead during attention)
  float* pml  = (float*)h_ln;          // 512 KB <= h_ln (dead during attention)

  const dim3 blk(256);
  const dim3 blk5(512);
  const dim3 g_q(D_EMB / 128, (NB * NQ) / 128);    // (16, 8)
  const dim3 g_kv256((NB * NS / 256) * (D_EMB / 256));  // 256 blocks
  const dim3 g_f1(FF / 128, (NB * NQ) / 128);      // (64, 8)
  const dim3 g_tw(D_EMB / 64, D_EMB / 64);
  const dim3 g_tf1(FF / 64, D_EMB / 64);
  const dim3 g_tf2(D_EMB / 64, FF / 64);
  const int  g_cvt = (int)(SZ_KV / 8 / 256);

  // ---- layer 1 ----
  cvt_kernel<<<g_cvt, blk, 0, stream>>>(xf1, xfb, (int)SZ_KV);
  ln_kernel<<<NB * NQ, blk, 0, stream>>>(x, L1[0], L1[1], h_ln);
  transpose_kernel<<<g_tw, blk, 0, stream>>>(L1[2], Wt, D_EMB, D_EMB);
  gemm_kernel<0,0><<<g_q,  blk, 0, stream>>>(h_ln, Wt, L1[3], nullptr, qh, NB * NQ, D_EMB, D_EMB);
  transpose_kernel<<<g_tw, blk, 0, stream>>>(L1[4], Wt, D_EMB, D_EMB);
  gemm256_kernel<0,0><<<g_kv256, blk5, 0, stream>>>(xfb, Wt, L1[5], nullptr, kh, NB * NS, D_EMB, D_EMB);
  transpose_kernel<<<g_tw, blk, 0, stream>>>(L1[6], Wt, D_EMB, D_EMB);
  gemm256_kernel<0,0><<<g_kv256, blk5, 0, stream>>>(xfb, Wt, L1[7], nullptr, vh, NB * NS, D_EMB, D_EMB);
  attn_part_kernel<<<1024, blk, 0, stream>>>(qh, kh, vh, po, pml);
  attn_combine_kernel<<<4096, blk, 0, stream>>>(qh, L1[10], L1[11], po, pml, ctxb);
  transpose_kernel<<<g_tw, blk, 0, stream>>>(L1[8], Wt, D_EMB, D_EMB);
  gemm_kernel<1,1><<<g_q,  blk, 0, stream>>>(ctxb, Wt, L1[9], x, x1, NB * NQ, D_EMB, D_EMB);

  // ---- layer 2 ----
  cvt_kernel<<<g_cvt, blk, 0, stream>>>(xf2, xfb, (int)SZ_KV);
  ln_kernel<<<NB * NQ, blk, 0, stream>>>(x1, L2[0], L2[1], h_ln);
  transpose_kernel<<<g_tw, blk, 0, stream>>>(L2[2], Wt, D_EMB, D_EMB);
  gemm_kernel<0,0><<<g_q,  blk, 0, stream>>>(h_ln, Wt, L2[3], nullptr, qh, NB * NQ, D_EMB, D_EMB);
  transpose_kernel<<<g_tw, blk, 0, stream>>>(L2[4], Wt, D_EMB, D_EMB);
  gemm256_kernel<0,0><<<g_kv256, blk5, 0, stream>>>(xfb, Wt, L2[5], nullptr, kh, NB * NS, D_EMB, D_EMB);
  transpose_kernel<<<g_tw, blk, 0, stream>>>(L2[6], Wt, D_EMB, D_EMB);
  gemm256_kernel<0,0><<<g_kv256, blk5, 0, stream>>>(xfb, Wt, L2[7], nullptr, vh, NB * NS, D_EMB, D_EMB);
  attn_part_kernel<<<1024, blk, 0, stream>>>(qh, kh, vh, po, pml);
  attn_combine_kernel<<<4096, blk, 0, stream>>>(qh, L2[10], L2[11], po, pml, ctxb);
  transpose_kernel<<<g_tw, blk, 0, stream>>>(L2[8], Wt, D_EMB, D_EMB);
  gemm_kernel<1,1><<<g_q,  blk, 0, stream>>>(ctxb, Wt, L2[9], x1, x2, NB * NQ, D_EMB, D_EMB);

  // ---- MLP ----
  ln_kernel<<<NB * NQ, blk, 0, stream>>>(x2, ln_mlp_s, ln_mlp_o, h_ln);
  transpose_kernel<<<g_tf1, blk, 0, stream>>>(w_fc1, Wt, D_EMB, FF);
  gemm_kernel<2,0><<<g_f1, blk, 0, stream>>>(h_ln, Wt, b_fc1, nullptr, fc1b, NB * NQ, FF, D_EMB);
  transpose_kernel<<<g_tf2, blk, 0, stream>>>(w_fc2, Wt, FF, D_EMB);
  gemm_kernel<1,1><<<g_q,  blk, 0, stream>>>(fc1b, Wt, b_fc2, x2, out, NB * NQ, D_EMB, FF);
}

// Round 4
// 1173.217 us; speedup vs baseline: 1.3908x; 1.1068x over previous
//
#include <hip/hip_runtime.h>

typedef __attribute__((ext_vector_type(8))) short bf16x8;
typedef __attribute__((ext_vector_type(4))) short short4v;
typedef __attribute__((ext_vector_type(4))) float f32x4;

#define D_EMB 2048
#define NQ    256
#define NB    4
#define NS    2048
#define NH    16
#define HK    128
#define FF    8192

__device__ __forceinline__ float b2f(short s) {
  union { unsigned int u; float f; } c;
  c.u = ((unsigned int)(unsigned short)s) << 16;
  return c.f;
}
__device__ __forceinline__ short f2b(float f) {
  union { float f; unsigned int u; } c; c.f = f;
  unsigned int u = c.u;
  u += 0x7FFFu + ((u >> 16) & 1u);   // RNE
  return (short)(u >> 16);
}
__device__ __forceinline__ void gload_lds16(const short* g, short* l) {
  __builtin_amdgcn_global_load_lds(
      (const __attribute__((address_space(1))) void*)g,
      (__attribute__((address_space(3))) void*)l, 16, 0, 0);
}

// ---------------- elementwise fp32 -> bf16 ----------------
__global__ __launch_bounds__(256)
void cvt_kernel(const float* __restrict__ in, short* __restrict__ out, int n8) {
  const int i = (blockIdx.x * 256 + threadIdx.x) * 8;
  if (i >= n8) return;
  f32x4 a = *(const f32x4*)(in + i), b = *(const f32x4*)(in + i + 4);
  bf16x8 t;
#pragma unroll
  for (int j = 0; j < 4; ++j) { t[j] = f2b(a[j]); t[4 + j] = f2b(b[j]); }
  *(bf16x8*)(out + i) = t;
}

// ---------------- W[Kd,N] fp32 -> Wt[N,Kd] bf16 (64x64 tiles) ----------------
__global__ __launch_bounds__(256)
void transpose_kernel(const float* __restrict__ W, short* __restrict__ Wt,
                      int Kd, int N) {
  __shared__ short tile[64][65];   // [n][k]
  const int k0 = blockIdx.y * 64, n0 = blockIdx.x * 64;
  const int tid = threadIdx.x;
  const int r = tid >> 2, c4 = (tid & 3) * 16;
#pragma unroll
  for (int i = 0; i < 16; i += 4) {
    f32x4 v = *(const f32x4*)(W + (size_t)(k0 + r) * N + n0 + c4 + i);
#pragma unroll
    for (int j = 0; j < 4; ++j) tile[c4 + i + j][r] = f2b(v[j]);
  }
  __syncthreads();
  bf16x8 o0, o1;
#pragma unroll
  for (int j = 0; j < 8; ++j) { o0[j] = tile[r][c4 + j]; o1[j] = tile[r][c4 + 8 + j]; }
  short* dst = Wt + (size_t)(n0 + r) * Kd + k0 + c4;
  *(bf16x8*)dst = o0;
  *(bf16x8*)(dst + 8) = o1;
}

// ---------------- LayerNorm (row = 2048), fp32 in -> bf16 out ----------------
__global__ __launch_bounds__(256)
void ln_kernel(const float* __restrict__ x, const float* __restrict__ scale,
               const float* __restrict__ offset, short* __restrict__ out) {
  const int row = blockIdx.x, tid = threadIdx.x;
  const float* xr = x + (size_t)row * D_EMB + tid * 8;
  f32x4 v0 = *(const f32x4*)xr;
  f32x4 v1 = *(const f32x4*)(xr + 4);
  float f[8], s = 0.f, sq = 0.f;
#pragma unroll
  for (int i = 0; i < 4; ++i) { f[i] = v0[i]; f[4 + i] = v1[i]; }
#pragma unroll
  for (int i = 0; i < 8; ++i) { s += f[i]; sq += f[i] * f[i]; }
#pragma unroll
  for (int off = 1; off < 64; off <<= 1) {
    s  += __shfl_xor(s, off, 64);
    sq += __shfl_xor(sq, off, 64);
  }
  __shared__ float red[2][4];
  const int w = tid >> 6;
  if ((tid & 63) == 0) { red[0][w] = s; red[1][w] = sq; }
  __syncthreads();
  s  = red[0][0] + red[0][1] + red[0][2] + red[0][3];
  sq = red[1][0] + red[1][1] + red[1][2] + red[1][3];
  const float mu  = s * (1.f / D_EMB);
  const float var = sq * (1.f / D_EMB) - mu * mu;
  const float inv = rsqrtf(var + 1e-5f);
  bf16x8 ov;
#pragma unroll
  for (int i = 0; i < 8; ++i) {
    const int c = tid * 8 + i;
    ov[i] = f2b((f[i] - mu) * inv * scale[c] + offset[c]);
  }
  *(bf16x8*)(out + (size_t)row * D_EMB + tid * 8) = ov;
}

// ---------------- GEMM 256x256, BK=64, 8-wave, 4-phase pipelined ----------------
// C = A[M,Kd] @ Bt[N,Kd]^T.  M%256==0, N%256==0, (Kd/SPLITK)%128==0, grid%8==0.
// SPLITK==1: epilogue bias/EPI/OUTF.  SPLITK>1: fp32 partials to Cp[split][M][N].
// LDS per buffer (shorts): A-k0 [0,8192) A-k1 [8192,16384) B-k0 [16384,24576)
// B-k1 [24576,32768).  Within a 16KB half: elem (r,kc) at (r>>3)*256+(kc>>3)*64+(r&7)*8.
// Staging: linear global_load_lds dest, per-lane pre-permuted global source.
#define FENCE() asm volatile("" ::: "memory")

#define G_STAGE(DB2, DSTOFF, PS0, PS1, KON)                                     \
  gload_lds16((PS0) + (KON), sh + (DB2) * 32768 + (DSTOFF) + tid * 8);          \
  gload_lds16((PS1) + (KON), sh + (DB2) * 32768 + (DSTOFF) + 4096 + tid * 8);

#define PHASE(DB, MG, KH, DSTOFF, PS0, PS1, KON, DOVM)                          \
  {                                                                             \
    const short* _ra = sh + (DB) * 32768 + (KH) * 8192;                         \
    const short* _rb = sh + (DB) * 32768 + 16384 + (KH) * 8192;                 \
    if ((MG) == 0) {                                                            \
      bfrag[0] = *(const bf16x8*)(_rb + boff[0]);                               \
      bfrag[1] = *(const bf16x8*)(_rb + boff[1]);                               \
      bfrag[2] = *(const bf16x8*)(_rb + boff[2]);                               \
      bfrag[3] = *(const bf16x8*)(_rb + boff[3]);                               \
    }                                                                           \
    afrag[0] = *(const bf16x8*)(_ra + aoff[(MG) * 4 + 0]);                      \
    afrag[1] = *(const bf16x8*)(_ra + aoff[(MG) * 4 + 1]);                      \
    afrag[2] = *(const bf16x8*)(_ra + aoff[(MG) * 4 + 2]);                      \
    afrag[3] = *(const bf16x8*)(_ra + aoff[(MG) * 4 + 3]);                      \
    G_STAGE((DB) ^ 1, DSTOFF, PS0, PS1, KON)                                    \
    if (DOVM) asm volatile("s_waitcnt vmcnt(4)" ::: "memory");                  \
    __builtin_amdgcn_s_barrier();                                               \
    FENCE();                                                                    \
    __builtin_amdgcn_s_setprio(1);                                              \
    _Pragma("unroll")                                                           \
    for (int mf = 0; mf < 4; ++mf)                                              \
      _Pragma("unroll")                                                         \
      for (int nf = 0; nf < 4; ++nf)                                            \
        acc[(MG) * 4 + mf][nf] = __builtin_amdgcn_mfma_f32_16x16x32_bf16(       \
            afrag[mf], bfrag[nf], acc[(MG) * 4 + mf][nf], 0, 0, 0);             \
    __builtin_amdgcn_s_setprio(0);                                              \
    __builtin_amdgcn_s_barrier();                                               \
    FENCE();                                                                    \
  }

#define TILE(DB, KON)                                                           \
  PHASE(DB, 0, 0, 0,     pA0, pA1, (KON), 0)                                    \
  PHASE(DB, 1, 0, 16384, pB0, pB1, (KON), 1)                                    \
  PHASE(DB, 0, 1, 8192,  pA0, pA1, (KON) + 32, 0)                               \
  PHASE(DB, 1, 1, 24576, pB0, pB1, (KON) + 32, 1)

template<int EPI, int OUTF, int SPLITK>
__global__ __launch_bounds__(512, 2)
void gemm256_kernel(const short* __restrict__ A, const short* __restrict__ Bt,
                    const float* __restrict__ bias, const float* __restrict__ res,
                    void* __restrict__ Cp, int M, int N, int Kd) {
  __shared__ short sh[65536];   // 128 KiB
  const int tid = threadIdx.x;
  const int w = tid >> 6, lane = tid & 63;
  const int l15 = lane & 15, quad = lane >> 4;
  const int wm = w >> 2, wn = w & 3;

  // XCD-chunked swizzle; tile-id m-major; for SPLITK>1 each XCD owns whole splits
  const int nTn = N >> 8;
  const int ntiles = (M >> 8) * nTn;
  const int cpx = gridDim.x >> 3;
  const int wid = (blockIdx.x & 7) * cpx + (blockIdx.x >> 3);
  const int tile  = (SPLITK == 1) ? wid : (wid % ntiles);
  const int split = (SPLITK == 1) ? 0   : (wid / ntiles);
  const int Ko = Kd / SPLITK;
  const int ks = split * Ko;
  const int m0 = (tile / nTn) * 256, n0 = (tile % nTn) * 256;

  // staging decode: chunk c covers LDS bytes [c*16, c*16+16) of a 16KB half;
  // that slot holds global elem (r, kb): r=(c>>5)*8+(c&7), kb=(c>>3)&3.
  const int c0 = tid, c1 = 512 + tid;
  const int r0 = ((c0 >> 5) << 3) + (c0 & 7), kb0 = (c0 >> 3) & 3;
  const int r1 = ((c1 >> 5) << 3) + (c1 & 7), kb1 = (c1 >> 3) & 3;
  const short* pA0 = A  + (size_t)(m0 + r0) * Kd + kb0 * 8;
  const short* pA1 = A  + (size_t)(m0 + r1) * Kd + kb1 * 8;
  const short* pB0 = Bt + (size_t)(n0 + r0) * Kd + kb0 * 8;
  const short* pB1 = Bt + (size_t)(n0 + r1) * Kd + kb1 * 8;

  // per-thread fragment read offsets (shorts, within a 16KB half)
  int aoff[8], boff[4];
#pragma unroll
  for (int mf = 0; mf < 8; ++mf) {
    const int r = wm * 128 + mf * 16 + l15;
    aoff[mf] = ((r >> 3) << 8) + (quad << 6) + ((r & 7) << 3);
  }
#pragma unroll
  for (int nf = 0; nf < 4; ++nf) {
    const int r = wn * 64 + nf * 16 + l15;
    boff[nf] = ((r >> 3) << 8) + (quad << 6) + ((r & 7) << 3);
  }

  f32x4 acc[8][4];
#pragma unroll
  for (int mf = 0; mf < 8; ++mf)
#pragma unroll
    for (int nf = 0; nf < 4; ++nf) acc[mf][nf] = (f32x4){0.f, 0.f, 0.f, 0.f};
  bf16x8 afrag[4], bfrag[4];

  const int NT = Ko >> 6;   // K-tiles of 64 in this split's chunk

  // prologue: stage tile 0 into buf0 (issue order = consumption order)
  G_STAGE(0, 0,     pA0, pA1, ks)
  G_STAGE(0, 16384, pB0, pB1, ks)
  G_STAGE(0, 8192,  pA0, pA1, ks + 32)
  G_STAGE(0, 24576, pB0, pB1, ks + 32)
  asm volatile("s_waitcnt vmcnt(4)" ::: "memory");   // A-k0,B-k0 of tile 0 landed
  __builtin_amdgcn_s_barrier();
  FENCE();

  for (int kt = 0; kt < NT; kt += 2) {
    const int k1n = ks + (kt + 1) * 64;                          // src of tile kt+1
    const int k2n = (kt + 2 < NT) ? ks + (kt + 2) * 64 : ks;     // wrap (unused data)
    TILE(0, k1n)
    TILE(1, k2n)
  }
  // drain before epilogue / block retire
  asm volatile("s_waitcnt vmcnt(0) lgkmcnt(0)" ::: "memory");

  if (SPLITK == 1) {
#pragma unroll
    for (int mf = 0; mf < 8; ++mf) {
#pragma unroll
      for (int nf = 0; nf < 4; ++nf) {
        const int gn = n0 + wn * 64 + nf * 16 + l15;
        const float bv = bias[gn];
#pragma unroll
        for (int r = 0; r < 4; ++r) {
          const int gm = m0 + wm * 128 + mf * 16 + quad * 4 + r;
          float v = acc[mf][nf][r] + bv;
          if (EPI == 1) v += res[(size_t)gm * N + gn];
          if (EPI == 2) v = 0.5f * v * (1.f + erff(v * 0.70710678118654752f));
          if (OUTF) ((float*)Cp)[(size_t)gm * N + gn] = v;
          else      ((short*)Cp)[(size_t)gm * N + gn] = f2b(v);
        }
      }
    }
  } else {
    float* po = (float*)Cp + (size_t)split * M * N;
#pragma unroll
    for (int mf = 0; mf < 8; ++mf) {
#pragma unroll
      for (int nf = 0; nf < 4; ++nf) {
        const int gn = n0 + wn * 64 + nf * 16 + l15;
#pragma unroll
        for (int r = 0; r < 4; ++r) {
          const int gm = m0 + wm * 128 + mf * 16 + quad * 4 + r;
          po[(size_t)gm * N + gn] = acc[mf][nf][r];
        }
      }
    }
  }
}

// ---------------- split-K combine: sum S partials + bias + epilogue ----------------
// EPI: 0 none, 1 +res(fp32), 2 exact gelu.  OUTF: 1 fp32, 0 bf16.
template<int S, int EPI, int OUTF>
__global__ __launch_bounds__(256)
void combine_kernel(const float* __restrict__ po, const float* __restrict__ bias,
                    const float* __restrict__ res, void* __restrict__ out,
                    int M, int N) {
  const size_t i4 = ((size_t)blockIdx.x * 256 + threadIdx.x) * 4;
  if (i4 >= (size_t)M * N) return;
  const int n = (int)(i4 % N);
  f32x4 s = *(const f32x4*)(po + i4);
#pragma unroll
  for (int sp = 1; sp < S; ++sp) {
    const f32x4 p = *(const f32x4*)(po + (size_t)sp * M * N + i4);
#pragma unroll
    for (int j = 0; j < 4; ++j) s[j] += p[j];
  }
  const f32x4 bv = *(const f32x4*)(bias + n);
#pragma unroll
  for (int j = 0; j < 4; ++j) s[j] += bv[j];
  if (EPI == 1) {
    const f32x4 rv = *(const f32x4*)(res + i4);
#pragma unroll
    for (int j = 0; j < 4; ++j) s[j] += rv[j];
  }
  if (EPI == 2) {
#pragma unroll
    for (int j = 0; j < 4; ++j)
      s[j] = 0.5f * s[j] * (1.f + erff(s[j] * 0.70710678118654752f));
  }
  if (OUTF) {
    *(f32x4*)((float*)out + i4) = s;
  } else {
    short4v o;
#pragma unroll
    for (int j = 0; j < 4; ++j) o[j] = f2b(s[j]);
    *(short4v*)((short*)out + i4) = o;
  }
}

// ---------------- Flash cross-attention, 4-way KV split (partials) ----------------
__global__ __launch_bounds__(256)
void attn_part_kernel(const short* __restrict__ qh, const short* __restrict__ kh,
                      const short* __restrict__ vh, float* __restrict__ po,
                      float* __restrict__ pml) {
  const int bx = blockIdx.x;
  const int work = (bx & 7) * 128 + (bx >> 3);   // XCD-contiguous work id
  const int bh = work >> 4, sub = work & 15;
  const int qt = sub >> 2, split = sub & 3;
  const int b = bh >> 4, h = bh & 15;
  const int tid = threadIdx.x, w = tid >> 6, lane = tid & 63;
  const int l15 = lane & 15, quad = lane >> 4;
  const int q0 = qt * 64 + w * 16;

  __shared__ short ldsK[32 * 128];   // [t][d], XOR-swizzled by (t&7)<<4 bytes
  __shared__ short ldsV[128 * 32];   // [d][t], XOR-swizzled by ((d>>3)&3)<<4 bytes
  __shared__ short ldsP[4 * 16 * 32];// per-wave [q][t], XOR-swizzled by ((q>>1)&3)<<4

  const float sc = 0.08838834764831845f;

  bf16x8 aq[4];
  {
    const short* qrow = qh + ((size_t)(b * 256 + q0 + l15)) * D_EMB + h * 128;
#pragma unroll
    for (int s = 0; s < 4; ++s)
      aq[s] = *(const bf16x8*)(qrow + s * 32 + quad * 8);
  }

  f32x4 o[8];
  float m_run[4], l_run[4];
#pragma unroll
  for (int dt = 0; dt < 8; ++dt) o[dt] = (f32x4){0.f, 0.f, 0.f, 0.f};
#pragma unroll
  for (int r = 0; r < 4; ++r) { m_run[r] = -INFINITY; l_run[r] = 0.f; }

  const int srow = tid >> 4;
  const int j = tid & 15;
  const int ksw = (j ^ (srow & 7)) * 8;
  const int t_beg = split * 512;

  for (int t0 = t_beg; t0 < t_beg + 512; t0 += 32) {
    __syncthreads();
    const size_t kb0 = ((size_t)(b * NS + t0 + srow)) * D_EMB + h * 128;
    const size_t kb1 = kb0 + (size_t)16 * D_EMB;
    gload_lds16(kh + kb0 + ksw, ldsK + tid * 8);
    gload_lds16(kh + kb1 + ksw, ldsK + 2048 + tid * 8);
    {
      bf16x8 v0 = *(const bf16x8*)(vh + kb0 + j * 8);
      bf16x8 v1 = *(const bf16x8*)(vh + kb1 + j * 8);
#pragma unroll
      for (int i = 0; i < 8; ++i) {
        const int d = j * 8 + i;
        const int swz = ((d >> 3) & 3) << 4;
        char* base = (char*)ldsV + (d << 6);
        *(short*)(base + ((srow << 1) ^ swz))        = v0[i];
        *(short*)(base + (((srow + 16) << 1) ^ swz)) = v1[i];
      }
    }
    __syncthreads();

    f32x4 s0 = (f32x4){0.f, 0.f, 0.f, 0.f}, s1 = (f32x4){0.f, 0.f, 0.f, 0.f};
    const int kswr = (l15 & 7) << 4;
#pragma unroll
    for (int s = 0; s < 4; ++s) {
      const int cb = s * 64 + quad * 16;
      bf16x8 k0f = *(bf16x8*)((char*)ldsK + (l15 << 8)        + (cb ^ kswr));
      bf16x8 k1f = *(bf16x8*)((char*)ldsK + ((16 + l15) << 8) + (cb ^ kswr));
      s0 = __builtin_amdgcn_mfma_f32_16x16x32_bf16(aq[s], k0f, s0, 0, 0, 0);
      s1 = __builtin_amdgcn_mfma_f32_16x16x32_bf16(aq[s], k1f, s1, 0, 0, 0);
    }

    float alpha_r[4];
#pragma unroll
    for (int r = 0; r < 4; ++r) {
      const float v0 = s0[r] * sc, v1 = s1[r] * sc;
      float mx = fmaxf(v0, v1);
#pragma unroll
      for (int off = 1; off < 16; off <<= 1) mx = fmaxf(mx, __shfl_xor(mx, off, 16));
      const float m_new = fmaxf(m_run[r], mx);
      const float p0 = expf(v0 - m_new), p1 = expf(v1 - m_new);
      float rs = p0 + p1;
#pragma unroll
      for (int off = 1; off < 16; off <<= 1) rs += __shfl_xor(rs, off, 16);
      alpha_r[r] = expf(m_run[r] - m_new);
      l_run[r] = l_run[r] * alpha_r[r] + rs;
      m_run[r] = m_new;
      const int prow = quad * 4 + r;
      const int psw = ((prow >> 1) & 3) << 4;
      char* pb = (char*)ldsP + w * 1024 + (prow << 6);
      *(short*)(pb + ((l15 << 1) ^ psw))        = f2b(p0);
      *(short*)(pb + (((16 + l15) << 1) ^ psw)) = f2b(p1);
    }
#pragma unroll
    for (int dt = 0; dt < 8; ++dt)
#pragma unroll
      for (int r = 0; r < 4; ++r) o[dt][r] *= alpha_r[r];

    bf16x8 pf = *(bf16x8*)((char*)ldsP + w * 1024 + (l15 << 6) +
                           ((quad << 4) ^ (((l15 >> 1) & 3) << 4)));
#pragma unroll
    for (int dt = 0; dt < 8; ++dt) {
      const int drow = dt * 16 + l15;
      bf16x8 vf = *(bf16x8*)((char*)ldsV + (drow << 6) +
                             ((quad << 4) ^ (((drow >> 3) & 3) << 4)));
      o[dt] = __builtin_amdgcn_mfma_f32_16x16x32_bf16(pf, vf, o[dt], 0, 0, 0);
    }
  }

  const int orow_base = (bh * 4 + qt) * 64 + w * 16;
#pragma unroll
  for (int dt = 0; dt < 8; ++dt)
#pragma unroll
    for (int r = 0; r < 4; ++r) {
      const size_t orow = (size_t)(orow_base + quad * 4 + r);
      po[(orow * 4 + split) * 128 + dt * 16 + l15] = o[dt][r];
    }
  if (l15 == 0) {
#pragma unroll
    for (int r = 0; r < 4; ++r) {
      const size_t orow = (size_t)(orow_base + quad * 4 + r);
      pml[(orow * 4 + split) * 2]     = m_run[r];
      pml[(orow * 4 + split) * 2 + 1] = l_run[r];
    }
  }
}

// ---------------- combine attn partials + learned bias kv position ----------------
__global__ __launch_bounds__(256)
void attn_combine_kernel(const short* __restrict__ qh, const float* __restrict__ bias_k,
                         const float* __restrict__ bias_v, const float* __restrict__ po,
                         const float* __restrict__ pml, short* __restrict__ ctx) {
  const int tid = threadIdx.x, w = tid >> 6, lane = tid & 63;
  const int task = blockIdx.x * 4 + w;            // 0..16383
  const int bh = task >> 8, qr = task & 255;
  const int b = bh >> 4, h = bh & 15;
  const int d0 = lane * 2;
  const float sc = 0.08838834764831845f;

  const short* qrow = qh + ((size_t)(b * 256 + qr)) * D_EMB + h * 128 + d0;
  const unsigned int qv = *(const unsigned int*)qrow;
  const float q0 = b2f((short)(qv & 0xffffu));
  const float q1 = b2f((short)(qv >> 16));
  const float2 bk = *(const float2*)(bias_k + h * 128 + d0);
  float le = q0 * bk.x + q1 * bk.y;
#pragma unroll
  for (int off = 1; off < 64; off <<= 1) le += __shfl_xor(le, off, 64);
  le *= sc;

  const float* pm = pml + (size_t)task * 8;
  float m[4], l[4];
#pragma unroll
  for (int s = 0; s < 4; ++s) { m[s] = pm[s * 2]; l[s] = pm[s * 2 + 1]; }
  float mt = le;
#pragma unroll
  for (int s = 0; s < 4; ++s) mt = fmaxf(mt, m[s]);

  const float pe = expf(le - mt);
  const float2 bv = *(const float2*)(bias_v + h * 128 + d0);
  float acc0 = pe * bv.x, acc1 = pe * bv.y;
  float lt = pe;
#pragma unroll
  for (int s = 0; s < 4; ++s) {
    const float es = expf(m[s] - mt);
    lt += l[s] * es;
    const float2 op = *(const float2*)(po + ((size_t)task * 4 + s) * 128 + d0);
    acc0 += es * op.x;
    acc1 += es * op.y;
  }
  const float inv = 1.f / lt;
  const unsigned int pack =
      ((unsigned int)(unsigned short)f2b(acc1 * inv) << 16) |
      (unsigned short)f2b(acc0 * inv);
  *(unsigned int*)(ctx + ((size_t)(b * 256 + qr)) * D_EMB + h * 128 + d0) = pack;
}

extern "C" void kernel_launch(void* const* d_in, const int* in_sizes, int n_in,
                              void* d_out, int out_size, void* d_ws, size_t ws_size,
                              hipStream_t stream) {
  const float* x   = (const float*)d_in[0];
  const float* xf1 = (const float*)d_in[1];
  const float* xf2 = (const float*)d_in[2];
  const float* L1[12]; const float* L2[12];
  for (int j = 0; j < 12; ++j) { L1[j] = (const float*)d_in[3 + j]; L2[j] = (const float*)d_in[15 + j]; }
  const float* ln_mlp_s = (const float*)d_in[27];
  const float* ln_mlp_o = (const float*)d_in[28];
  const float* w_fc1    = (const float*)d_in[29];
  const float* b_fc1    = (const float*)d_in[30];
  const float* w_fc2    = (const float*)d_in[31];
  const float* b_fc2    = (const float*)d_in[32];
  float* out = (float*)d_out;

  const size_t SZ_XQ  = (size_t)NB * NQ * D_EMB;   // 2M elems
  const size_t SZ_KV  = (size_t)NB * NS * D_EMB;   // 16.8M elems

  float* x1   = (float*)d_ws;
  float* x2   = x1 + SZ_XQ;
  short* h_ln = (short*)(x2 + SZ_XQ);
  short* qh   = h_ln + SZ_XQ;
  short* ctxb = qh + SZ_XQ;
  short* kh   = ctxb + SZ_XQ;
  short* vh   = kh + SZ_KV;
  short* xfb  = vh + SZ_KV;
  short* Wt   = xfb + SZ_KV;
  short* fc1b = kh;                    // alias: kh dead by MLP time
  float* po   = (float*)Wt;            // attn partials alias (Wt dead during attention)
  float* pml  = (float*)h_ln;          // 512 KB <= h_ln (dead during attention)
  float* pk1  = (float*)kh;            // split-K partials: kh∪vh = 67 MB (dead at proj time)
  float* pk2  = (float*)vh;            // split-K partials: vh∪xfb = 67 MB (dead at MLP time)

  const dim3 blk(256);
  const dim3 blk5(512);
  const dim3 g_kv256((NB * NS / 256) * (D_EMB / 256));  // 256 blocks
  const dim3 g_sk(256);                                 // all split-K gemms
  const dim3 g_skf1(256);
  const dim3 g_cb2(2048);                               // combine 1024x2048
  const dim3 g_cb8(8192);                               // combine 1024x8192
  const dim3 g_tw(D_EMB / 64, D_EMB / 64);
  const dim3 g_tf1(FF / 64, D_EMB / 64);
  const dim3 g_tf2(D_EMB / 64, FF / 64);
  const int  g_cvt = (int)(SZ_KV / 8 / 256);

  // ---- layer 1 ----
  cvt_kernel<<<g_cvt, blk, 0, stream>>>(xf1, xfb, (int)SZ_KV);
  ln_kernel<<<NB * NQ, blk, 0, stream>>>(x, L1[0], L1[1], h_ln);
  transpose_kernel<<<g_tw, blk, 0, stream>>>(L1[2], Wt, D_EMB, D_EMB);
  gemm256_kernel<0,0,8><<<g_sk, blk5, 0, stream>>>(h_ln, Wt, nullptr, nullptr, pk1, NB * NQ, D_EMB, D_EMB);
  combine_kernel<8,0,0><<<g_cb2, blk, 0, stream>>>(pk1, L1[3], nullptr, qh, NB * NQ, D_EMB);
  transpose_kernel<<<g_tw, blk, 0, stream>>>(L1[4], Wt, D_EMB, D_EMB);
  gemm256_kernel<0,0,1><<<g_kv256, blk5, 0, stream>>>(xfb, Wt, L1[5], nullptr, kh, NB * NS, D_EMB, D_EMB);
  transpose_kernel<<<g_tw, blk, 0, stream>>>(L1[6], Wt, D_EMB, D_EMB);
  gemm256_kernel<0,0,1><<<g_kv256, blk5, 0, stream>>>(xfb, Wt, L1[7], nullptr, vh, NB * NS, D_EMB, D_EMB);
  attn_part_kernel<<<1024, blk, 0, stream>>>(qh, kh, vh, po, pml);
  attn_combine_kernel<<<4096, blk, 0, stream>>>(qh, L1[10], L1[11], po, pml, ctxb);
  transpose_kernel<<<g_tw, blk, 0, stream>>>(L1[8], Wt, D_EMB, D_EMB);
  gemm256_kernel<0,0,8><<<g_sk, blk5, 0, stream>>>(ctxb, Wt, nullptr, nullptr, pk1, NB * NQ, D_EMB, D_EMB);
  combine_kernel<8,1,1><<<g_cb2, blk, 0, stream>>>(pk1, L1[9], x, x1, NB * NQ, D_EMB);

  // ---- layer 2 ----
  cvt_kernel<<<g_cvt, blk, 0, stream>>>(xf2, xfb, (int)SZ_KV);
  ln_kernel<<<NB * NQ, blk, 0, stream>>>(x1, L2[0], L2[1], h_ln);
  transpose_kernel<<<g_tw, blk, 0, stream>>>(L2[2], Wt, D_EMB, D_EMB);
  gemm256_kernel<0,0,8><<<g_sk, blk5, 0, stream>>>(h_ln, Wt, nullptr, nullptr, pk1, NB * NQ, D_EMB, D_EMB);
  combine_kernel<8,0,0><<<g_cb2, blk, 0, stream>>>(pk1, L2[3], nullptr, qh, NB * NQ, D_EMB);
  transpose_kernel<<<g_tw, blk, 0, stream>>>(L2[4], Wt, D_EMB, D_EMB);
  gemm256_kernel<0,0,1><<<g_kv256, blk5, 0, stream>>>(xfb, Wt, L2[5], nullptr, kh, NB * NS, D_EMB, D_EMB);
  transpose_kernel<<<g_tw, blk, 0, stream>>>(L2[6], Wt, D_EMB, D_EMB);
  gemm256_kernel<0,0,1><<<g_kv256, blk5, 0, stream>>>(xfb, Wt, L2[7], nullptr, vh, NB * NS, D_EMB, D_EMB);
  attn_part_kernel<<<1024, blk, 0, stream>>>(qh, kh, vh, po, pml);
  attn_combine_kernel<<<4096, blk, 0, stream>>>(qh, L2[10], L2[11], po, pml, ctxb);
  transpose_kernel<<<g_tw, blk, 0, stream>>>(L2[8], Wt, D_EMB, D_EMB);
  gemm256_kernel<0,0,8><<<g_sk, blk5, 0, stream>>>(ctxb, Wt, nullptr, nullptr, pk1, NB * NQ, D_EMB, D_EMB);
  combine_kernel<8,1,1><<<g_cb2, blk, 0, stream>>>(pk1, L2[9], x1, x2, NB * NQ, D_EMB);

  // ---- MLP ----
  ln_kernel<<<NB * NQ, blk, 0, stream>>>(x2, ln_mlp_s, ln_mlp_o, h_ln);
  transpose_kernel<<<g_tf1, blk, 0, stream>>>(w_fc1, Wt, D_EMB, FF);
  gemm256_kernel<0,0,2><<<g_skf1, blk5, 0, stream>>>(h_ln, Wt, nullptr, nullptr, pk2, NB * NQ, FF, D_EMB);
  combine_kernel<2,2,0><<<g_cb8, blk, 0, stream>>>(pk2, b_fc1, nullptr, fc1b, NB * NQ, FF);
  transpose_kernel<<<g_tf2, blk, 0, stream>>>(w_fc2, Wt, FF, D_EMB);
  gemm256_kernel<0,0,8><<<g_sk, blk5, 0, stream>>>(fc1b, Wt, nullptr, nullptr, pk2, NB * NQ, D_EMB, FF);
  combine_kernel<8,1,1><<<g_cb2, blk, 0, stream>>>(pk2, b_fc2, x2, out, NB * NQ, D_EMB);
}

// Round 5
// 1112.415 us; speedup vs baseline: 1.4668x; 1.0547x over previous
//
#include <hip/hip_runtime.h>

typedef __attribute__((ext_vector_type(8))) short bf16x8;
typedef __attribute__((ext_vector_type(4))) short short4v;
typedef __attribute__((ext_vector_type(4))) float f32x4;

#define D_EMB 2048
#define NQ    256
#define NB    4
#define NS    2048
#define NH    16
#define HK    128
#define FF    8192

__device__ __forceinline__ float b2f(short s) {
  union { unsigned int u; float f; } c;
  c.u = ((unsigned int)(unsigned short)s) << 16;
  return c.f;
}
__device__ __forceinline__ short f2b(float f) {
  union { float f; unsigned int u; } c; c.f = f;
  unsigned int u = c.u;
  u += 0x7FFFu + ((u >> 16) & 1u);   // RNE
  return (short)(u >> 16);
}
__device__ __forceinline__ void gload_lds16(const short* g, short* l) {
  __builtin_amdgcn_global_load_lds(
      (const __attribute__((address_space(1))) void*)g,
      (__attribute__((address_space(3))) void*)l, 16, 0, 0);
}

// ---------------- elementwise fp32 -> bf16 ----------------
__global__ __launch_bounds__(256)
void cvt_kernel(const float* __restrict__ in, short* __restrict__ out, int n8) {
  const int i = (blockIdx.x * 256 + threadIdx.x) * 8;
  if (i >= n8) return;
  f32x4 a = *(const f32x4*)(in + i), b = *(const f32x4*)(in + i + 4);
  bf16x8 t;
#pragma unroll
  for (int j = 0; j < 4; ++j) { t[j] = f2b(a[j]); t[4 + j] = f2b(b[j]); }
  *(bf16x8*)(out + i) = t;
}

// ---------------- W[Kd,N] fp32 -> Wt[N,Kd] bf16 (64x64 tiles) ----------------
__global__ __launch_bounds__(256)
void transpose_kernel(const float* __restrict__ W, short* __restrict__ Wt,
                      int Kd, int N) {
  __shared__ short tile[64][65];   // [n][k]
  const int k0 = blockIdx.y * 64, n0 = blockIdx.x * 64;
  const int tid = threadIdx.x;
  const int r = tid >> 2, c4 = (tid & 3) * 16;
#pragma unroll
  for (int i = 0; i < 16; i += 4) {
    f32x4 v = *(const f32x4*)(W + (size_t)(k0 + r) * N + n0 + c4 + i);
#pragma unroll
    for (int j = 0; j < 4; ++j) tile[c4 + i + j][r] = f2b(v[j]);
  }
  __syncthreads();
  bf16x8 o0, o1;
#pragma unroll
  for (int j = 0; j < 8; ++j) { o0[j] = tile[r][c4 + j]; o1[j] = tile[r][c4 + 8 + j]; }
  short* dst = Wt + (size_t)(n0 + r) * Kd + k0 + c4;
  *(bf16x8*)dst = o0;
  *(bf16x8*)(dst + 8) = o1;
}

// ---------------- LayerNorm (row = 2048), fp32 in -> bf16 out ----------------
__global__ __launch_bounds__(256)
void ln_kernel(const float* __restrict__ x, const float* __restrict__ scale,
               const float* __restrict__ offset, short* __restrict__ out) {
  const int row = blockIdx.x, tid = threadIdx.x;
  const float* xr = x + (size_t)row * D_EMB + tid * 8;
  f32x4 v0 = *(const f32x4*)xr;
  f32x4 v1 = *(const f32x4*)(xr + 4);
  float f[8], s = 0.f, sq = 0.f;
#pragma unroll
  for (int i = 0; i < 4; ++i) { f[i] = v0[i]; f[4 + i] = v1[i]; }
#pragma unroll
  for (int i = 0; i < 8; ++i) { s += f[i]; sq += f[i] * f[i]; }
#pragma unroll
  for (int off = 1; off < 64; off <<= 1) {
    s  += __shfl_xor(s, off, 64);
    sq += __shfl_xor(sq, off, 64);
  }
  __shared__ float red[2][4];
  const int w = tid >> 6;
  if ((tid & 63) == 0) { red[0][w] = s; red[1][w] = sq; }
  __syncthreads();
  s  = red[0][0] + red[0][1] + red[0][2] + red[0][3];
  sq = red[1][0] + red[1][1] + red[1][2] + red[1][3];
  const float mu  = s * (1.f / D_EMB);
  const float var = sq * (1.f / D_EMB) - mu * mu;
  const float inv = rsqrtf(var + 1e-5f);
  bf16x8 ov;
#pragma unroll
  for (int i = 0; i < 8; ++i) {
    const int c = tid * 8 + i;
    ov[i] = f2b((f[i] - mu) * inv * scale[c] + offset[c]);
  }
  *(bf16x8*)(out + (size_t)row * D_EMB + tid * 8) = ov;
}

// ---------------- GEMM 256x256, BK=64, 8-wave, 4-phase pipelined ----------------
// C = A[M,Kd] @ Bt[N,Kd]^T.  M%256==0, N%256==0, (Kd/SPLITK)%128==0, grid%8==0.
// SPLITK==1: epilogue bias/EPI/OUTF.  SPLITK>1: fp32 partials to Cp[split][M][N].
// TRANSP==1 (requires SPLITK==1): writes bf16 C^T as [b][n][t] (row stride NS=2048,
// tile spans one b since 256 | 2048), bias added pre-transpose, via LDS bounce.
#define FENCE() asm volatile("" ::: "memory")

#define G_STAGE(DB2, DSTOFF, PS0, PS1, KON)                                     \
  gload_lds16((PS0) + (KON), sh + (DB2) * 32768 + (DSTOFF) + tid * 8);          \
  gload_lds16((PS1) + (KON), sh + (DB2) * 32768 + (DSTOFF) + 4096 + tid * 8);

#define PHASE(DB, MG, KH, DSTOFF, PS0, PS1, KON, DOVM)                          \
  {                                                                             \
    const short* _ra = sh + (DB) * 32768 + (KH) * 8192;                         \
    const short* _rb = sh + (DB) * 32768 + 16384 + (KH) * 8192;                 \
    if ((MG) == 0) {                                                            \
      bfrag[0] = *(const bf16x8*)(_rb + boff[0]);                               \
      bfrag[1] = *(const bf16x8*)(_rb + boff[1]);                               \
      bfrag[2] = *(const bf16x8*)(_rb + boff[2]);                               \
      bfrag[3] = *(const bf16x8*)(_rb + boff[3]);                               \
    }                                                                           \
    afrag[0] = *(const bf16x8*)(_ra + aoff[(MG) * 4 + 0]);                      \
    afrag[1] = *(const bf16x8*)(_ra + aoff[(MG) * 4 + 1]);                      \
    afrag[2] = *(const bf16x8*)(_ra + aoff[(MG) * 4 + 2]);                      \
    afrag[3] = *(const bf16x8*)(_ra + aoff[(MG) * 4 + 3]);                      \
    G_STAGE((DB) ^ 1, DSTOFF, PS0, PS1, KON)                                    \
    if (DOVM) asm volatile("s_waitcnt vmcnt(4)" ::: "memory");                  \
    __builtin_amdgcn_s_barrier();                                               \
    FENCE();                                                                    \
    __builtin_amdgcn_s_setprio(1);                                              \
    _Pragma("unroll")                                                           \
    for (int mf = 0; mf < 4; ++mf)                                              \
      _Pragma("unroll")                                                         \
      for (int nf = 0; nf < 4; ++nf)                                            \
        acc[(MG) * 4 + mf][nf] = __builtin_amdgcn_mfma_f32_16x16x32_bf16(       \
            afrag[mf], bfrag[nf], acc[(MG) * 4 + mf][nf], 0, 0, 0);             \
    __builtin_amdgcn_s_setprio(0);                                              \
    __builtin_amdgcn_s_barrier();                                               \
    FENCE();                                                                    \
  }

#define TILE(DB, KON)                                                           \
  PHASE(DB, 0, 0, 0,     pA0, pA1, (KON), 0)                                    \
  PHASE(DB, 1, 0, 16384, pB0, pB1, (KON), 1)                                    \
  PHASE(DB, 0, 1, 8192,  pA0, pA1, (KON) + 32, 0)                               \
  PHASE(DB, 1, 1, 24576, pB0, pB1, (KON) + 32, 1)

template<int EPI, int OUTF, int SPLITK, int TRANSP>
__global__ __launch_bounds__(512, 2)
void gemm256_kernel(const short* __restrict__ A, const short* __restrict__ Bt,
                    const float* __restrict__ bias, const float* __restrict__ res,
                    void* __restrict__ Cp, int M, int N, int Kd) {
  __shared__ short sh[65536];   // 128 KiB
  const int tid = threadIdx.x;
  const int w = tid >> 6, lane = tid & 63;
  const int l15 = lane & 15, quad = lane >> 4;
  const int wm = w >> 2, wn = w & 3;

  // XCD-chunked swizzle; tile-id m-major; for SPLITK>1 each XCD owns whole splits
  const int nTn = N >> 8;
  const int ntiles = (M >> 8) * nTn;
  const int cpx = gridDim.x >> 3;
  const int wid = (blockIdx.x & 7) * cpx + (blockIdx.x >> 3);
  const int tile  = (SPLITK == 1) ? wid : (wid % ntiles);
  const int split = (SPLITK == 1) ? 0   : (wid / ntiles);
  const int Ko = Kd / SPLITK;
  const int ks = split * Ko;
  const int m0 = (tile / nTn) * 256, n0 = (tile % nTn) * 256;

  // staging decode: chunk c covers LDS bytes [c*16, c*16+16) of a 16KB half;
  // that slot holds global elem (r, kb): r=(c>>5)*8+(c&7), kb=(c>>3)&3.
  const int c0 = tid, c1 = 512 + tid;
  const int r0 = ((c0 >> 5) << 3) + (c0 & 7), kb0 = (c0 >> 3) & 3;
  const int r1 = ((c1 >> 5) << 3) + (c1 & 7), kb1 = (c1 >> 3) & 3;
  const short* pA0 = A  + (size_t)(m0 + r0) * Kd + kb0 * 8;
  const short* pA1 = A  + (size_t)(m0 + r1) * Kd + kb1 * 8;
  const short* pB0 = Bt + (size_t)(n0 + r0) * Kd + kb0 * 8;
  const short* pB1 = Bt + (size_t)(n0 + r1) * Kd + kb1 * 8;

  // per-thread fragment read offsets (shorts, within a 16KB half)
  int aoff[8], boff[4];
#pragma unroll
  for (int mf = 0; mf < 8; ++mf) {
    const int r = wm * 128 + mf * 16 + l15;
    aoff[mf] = ((r >> 3) << 8) + (quad << 6) + ((r & 7) << 3);
  }
#pragma unroll
  for (int nf = 0; nf < 4; ++nf) {
    const int r = wn * 64 + nf * 16 + l15;
    boff[nf] = ((r >> 3) << 8) + (quad << 6) + ((r & 7) << 3);
  }

  f32x4 acc[8][4];
#pragma unroll
  for (int mf = 0; mf < 8; ++mf)
#pragma unroll
    for (int nf = 0; nf < 4; ++nf) acc[mf][nf] = (f32x4){0.f, 0.f, 0.f, 0.f};
  bf16x8 afrag[4], bfrag[4];

  const int NT = Ko >> 6;   // K-tiles of 64 in this split's chunk

  // prologue: stage tile 0 into buf0 (issue order = consumption order)
  G_STAGE(0, 0,     pA0, pA1, ks)
  G_STAGE(0, 16384, pB0, pB1, ks)
  G_STAGE(0, 8192,  pA0, pA1, ks + 32)
  G_STAGE(0, 24576, pB0, pB1, ks + 32)
  asm volatile("s_waitcnt vmcnt(4)" ::: "memory");   // A-k0,B-k0 of tile 0 landed
  __builtin_amdgcn_s_barrier();
  FENCE();

  for (int kt = 0; kt < NT; kt += 2) {
    const int k1n = ks + (kt + 1) * 64;                          // src of tile kt+1
    const int k2n = (kt + 2 < NT) ? ks + (kt + 2) * 64 : ks;     // wrap (unused data)
    TILE(0, k1n)
    TILE(1, k2n)
  }
  // drain before epilogue / block retire
  asm volatile("s_waitcnt vmcnt(0) lgkmcnt(0)" ::: "memory");

  if (TRANSP) {
    // bias + bf16, transpose in LDS (dword-index XOR swizzle by (n&3)<<2), then
    // coalesced C^T store: dst row = n (channel), cols = t within this tile's b.
    FENCE();
    const int bb = m0 >> 11;          // batch of this tile
    const int t0t = m0 & 2047;        // t offset of this tile
#pragma unroll
    for (int mf = 0; mf < 8; ++mf) {
      const int m_dw = wm * 64 + mf * 8 + quad * 2;   // dword idx of 4-row group
#pragma unroll
      for (int nf = 0; nf < 4; ++nf) {
        const int n_loc = wn * 64 + nf * 16 + l15;
        const float bv = bias[n0 + n_loc];
        short4v pk;
#pragma unroll
        for (int r = 0; r < 4; ++r) pk[r] = f2b(acc[mf][nf][r] + bv);
        const int m_sw = m_dw ^ ((n_loc & 3) << 2);
        *(short4v*)(sh + n_loc * 256 + (m_sw << 1)) = pk;
      }
    }
    __syncthreads();
#pragma unroll
    for (int it = 0; it < 16; ++it) {
      const int n_r = (tid >> 5) + it * 16;
      const int m_blk = tid & 31;
      const int m_sw = (m_blk << 2) ^ ((n_r & 3) << 2);
      const bf16x8 v = *(const bf16x8*)(sh + n_r * 256 + (m_sw << 1));
      short* dst = (short*)Cp + ((size_t)(bb * 2048) + n0 + n_r) * 2048 + t0t + m_blk * 8;
      *(bf16x8*)dst = v;
    }
  } else if (SPLITK == 1) {
#pragma unroll
    for (int mf = 0; mf < 8; ++mf) {
#pragma unroll
      for (int nf = 0; nf < 4; ++nf) {
        const int gn = n0 + wn * 64 + nf * 16 + l15;
        const float bv = bias[gn];
#pragma unroll
        for (int r = 0; r < 4; ++r) {
          const int gm = m0 + wm * 128 + mf * 16 + quad * 4 + r;
          float v = acc[mf][nf][r] + bv;
          if (EPI == 1) v += res[(size_t)gm * N + gn];
          if (EPI == 2) v = 0.5f * v * (1.f + erff(v * 0.70710678118654752f));
          if (OUTF) ((float*)Cp)[(size_t)gm * N + gn] = v;
          else      ((short*)Cp)[(size_t)gm * N + gn] = f2b(v);
        }
      }
    }
  } else {
    float* po = (float*)Cp + (size_t)split * M * N;
#pragma unroll
    for (int mf = 0; mf < 8; ++mf) {
#pragma unroll
      for (int nf = 0; nf < 4; ++nf) {
        const int gn = n0 + wn * 64 + nf * 16 + l15;
#pragma unroll
        for (int r = 0; r < 4; ++r) {
          const int gm = m0 + wm * 128 + mf * 16 + quad * 4 + r;
          po[(size_t)gm * N + gn] = acc[mf][nf][r];
        }
      }
    }
  }
}

// ---------------- split-K combine: sum S partials + bias + epilogue ----------------
template<int S, int EPI, int OUTF>
__global__ __launch_bounds__(256)
void combine_kernel(const float* __restrict__ po, const float* __restrict__ bias,
                    const float* __restrict__ res, void* __restrict__ out,
                    int M, int N) {
  const size_t i4 = ((size_t)blockIdx.x * 256 + threadIdx.x) * 4;
  if (i4 >= (size_t)M * N) return;
  const int n = (int)(i4 % N);
  f32x4 s = *(const f32x4*)(po + i4);
#pragma unroll
  for (int sp = 1; sp < S; ++sp) {
    const f32x4 p = *(const f32x4*)(po + (size_t)sp * M * N + i4);
#pragma unroll
    for (int j = 0; j < 4; ++j) s[j] += p[j];
  }
  const f32x4 bv = *(const f32x4*)(bias + n);
#pragma unroll
  for (int j = 0; j < 4; ++j) s[j] += bv[j];
  if (EPI == 1) {
    const f32x4 rv = *(const f32x4*)(res + i4);
#pragma unroll
    for (int j = 0; j < 4; ++j) s[j] += rv[j];
  }
  if (EPI == 2) {
#pragma unroll
    for (int j = 0; j < 4; ++j)
      s[j] = 0.5f * s[j] * (1.f + erff(s[j] * 0.70710678118654752f));
  }
  if (OUTF) {
    *(f32x4*)((float*)out + i4) = s;
  } else {
    short4v o;
#pragma unroll
    for (int j = 0; j < 4; ++j) o[j] = f2b(s[j]);
    *(short4v*)((short*)out + i4) = o;
  }
}

// ---------------- Flash cross-attention, 4-way KV split (partials) ----------------
// V supplied TRANSPOSED: vt[b][h*128+d][t] (row stride 2048).  l tracked via
// ones-MFMA row sum; defer-max (THR=8) skips rescale on non-growing tiles.
__global__ __launch_bounds__(256)
void attn_part_kernel(const short* __restrict__ qh, const short* __restrict__ kh,
                      const short* __restrict__ vt, float* __restrict__ po,
                      float* __restrict__ pml) {
  const int bx = blockIdx.x;
  const int work = (bx & 7) * 128 + (bx >> 3);   // XCD-contiguous work id
  const int bh = work >> 4, sub = work & 15;
  const int qt = sub >> 2, split = sub & 3;
  const int b = bh >> 4, h = bh & 15;
  const int tid = threadIdx.x, w = tid >> 6, lane = tid & 63;
  const int l15 = lane & 15, quad = lane >> 4;
  const int q0 = qt * 64 + w * 16;

  __shared__ short ldsK[32 * 128];   // [t][d], XOR-swizzled by (t&7)<<4 bytes
  __shared__ short ldsV[128 * 32];   // [d][t] linear (V^T staged direct)
  __shared__ short ldsP[4 * 16 * 32];// per-wave [q][t], XOR-swizzled by ((q>>1)&3)<<4

  const float sc = 0.08838834764831845f;
  const float THR = 8.f;

  bf16x8 aq[4];
  {
    const short* qrow = qh + ((size_t)(b * 256 + q0 + l15)) * D_EMB + h * 128;
#pragma unroll
    for (int s = 0; s < 4; ++s)
      aq[s] = *(const bf16x8*)(qrow + s * 32 + quad * 8);
  }
  bf16x8 ones;
#pragma unroll
  for (int i = 0; i < 8; ++i) ones[i] = (short)0x3F80;   // bf16 1.0

  f32x4 o[8];
  f32x4 o_sum = (f32x4){0.f, 0.f, 0.f, 0.f};
  float m_run[4];
#pragma unroll
  for (int dt = 0; dt < 8; ++dt) o[dt] = (f32x4){0.f, 0.f, 0.f, 0.f};
#pragma unroll
  for (int r = 0; r < 4; ++r) m_run[r] = -INFINITY;

  // K staging decode (pre-swizzled global source, linear LDS dest)
  const int srow = tid >> 4;
  const int ksw = ((tid & 15) ^ (srow & 7)) * 8;
  // V staging decode: chunk c = i*256+tid -> d = c>>2, tc = (c&3)*8
  const short* vt_base = vt + ((size_t)(b * 2048 + h * 128)) * 2048;
  const short* pv0 = vt_base + (size_t)(tid >> 2) * 2048 + (tid & 3) * 8;
  const short* pv1 = pv0 + (size_t)64 * 2048;

  const int t_beg = split * 512;

  for (int t0 = t_beg; t0 < t_beg + 512; t0 += 32) {
    __syncthreads();
    const size_t kb0 = ((size_t)(b * NS + t0 + srow)) * D_EMB + h * 128;
    const size_t kb1 = kb0 + (size_t)16 * D_EMB;
    gload_lds16(kh + kb0 + ksw, ldsK + tid * 8);
    gload_lds16(kh + kb1 + ksw, ldsK + 2048 + tid * 8);
    gload_lds16(pv0 + t0, ldsV + tid * 8);
    gload_lds16(pv1 + t0, ldsV + 2048 + tid * 8);
    __syncthreads();

    // QK^T
    f32x4 s0 = (f32x4){0.f, 0.f, 0.f, 0.f}, s1 = (f32x4){0.f, 0.f, 0.f, 0.f};
    const int kswr = (l15 & 7) << 4;
#pragma unroll
    for (int s = 0; s < 4; ++s) {
      const int cb = s * 64 + quad * 16;
      bf16x8 k0f = *(bf16x8*)((char*)ldsK + (l15 << 8)        + (cb ^ kswr));
      bf16x8 k1f = *(bf16x8*)((char*)ldsK + ((16 + l15) << 8) + (cb ^ kswr));
      s0 = __builtin_amdgcn_mfma_f32_16x16x32_bf16(aq[s], k0f, s0, 0, 0, 0);
      s1 = __builtin_amdgcn_mfma_f32_16x16x32_bf16(aq[s], k1f, s1, 0, 0, 0);
    }

    // defer-max online softmax
    int okl = 1;
#pragma unroll
    for (int r = 0; r < 4; ++r) {
      s0[r] *= sc; s1[r] *= sc;
      okl &= (s0[r] <= m_run[r] + THR) & (s1[r] <= m_run[r] + THR);
    }
    if (!__all(okl)) {
      float alpha_r[4];
#pragma unroll
      for (int r = 0; r < 4; ++r) {
        float mx = fmaxf(s0[r], s1[r]);
#pragma unroll
        for (int off = 1; off < 16; off <<= 1) mx = fmaxf(mx, __shfl_xor(mx, off, 16));
        const float m_new = fmaxf(m_run[r], mx);
        alpha_r[r] = expf(m_run[r] - m_new);
        m_run[r] = m_new;
      }
#pragma unroll
      for (int dt = 0; dt < 8; ++dt)
#pragma unroll
        for (int r = 0; r < 4; ++r) o[dt][r] *= alpha_r[r];
#pragma unroll
      for (int r = 0; r < 4; ++r) o_sum[r] *= alpha_r[r];
    }
#pragma unroll
    for (int r = 0; r < 4; ++r) {
      const float p0 = expf(s0[r] - m_run[r]);
      const float p1 = expf(s1[r] - m_run[r]);
      const int prow = quad * 4 + r;
      const int psw = ((prow >> 1) & 3) << 4;
      char* pb = (char*)ldsP + w * 1024 + (prow << 6);
      *(short*)(pb + ((l15 << 1) ^ psw))        = f2b(p0);
      *(short*)(pb + (((16 + l15) << 1) ^ psw)) = f2b(p1);
    }

    // PV + row-sum (ldsP per-wave: in-wave ordering, no barrier)
    bf16x8 pf = *(bf16x8*)((char*)ldsP + w * 1024 + (l15 << 6) +
                           ((quad << 4) ^ (((l15 >> 1) & 3) << 4)));
    o_sum = __builtin_amdgcn_mfma_f32_16x16x32_bf16(pf, ones, o_sum, 0, 0, 0);
#pragma unroll
    for (int dt = 0; dt < 8; ++dt) {
      bf16x8 vf = *(const bf16x8*)(ldsV + (dt * 16 + l15) * 32 + quad * 8);
      o[dt] = __builtin_amdgcn_mfma_f32_16x16x32_bf16(pf, vf, o[dt], 0, 0, 0);
    }
  }

  const int orow_base = (bh * 4 + qt) * 64 + w * 16;
#pragma unroll
  for (int dt = 0; dt < 8; ++dt)
#pragma unroll
    for (int r = 0; r < 4; ++r) {
      const size_t orow = (size_t)(orow_base + quad * 4 + r);
      po[(orow * 4 + split) * 128 + dt * 16 + l15] = o[dt][r];
    }
  if (l15 == 0) {
#pragma unroll
    for (int r = 0; r < 4; ++r) {
      const size_t orow = (size_t)(orow_base + quad * 4 + r);
      pml[(orow * 4 + split) * 2]     = m_run[r];
      pml[(orow * 4 + split) * 2 + 1] = o_sum[r];
    }
  }
}

// ---------------- combine attn partials + learned bias kv position ----------------
__global__ __launch_bounds__(256)
void attn_combine_kernel(const short* __restrict__ qh, const float* __restrict__ bias_k,
                         const float* __restrict__ bias_v, const float* __restrict__ po,
                         const float* __restrict__ pml, short* __restrict__ ctx) {
  const int tid = threadIdx.x, w = tid >> 6, lane = tid & 63;
  const int task = blockIdx.x * 4 + w;            // 0..16383
  const int bh = task >> 8, qr = task & 255;
  const int b = bh >> 4, h = bh & 15;
  const int d0 = lane * 2;
  const float sc = 0.08838834764831845f;

  const short* qrow = qh + ((size_t)(b * 256 + qr)) * D_EMB + h * 128 + d0;
  const unsigned int qv = *(const unsigned int*)qrow;
  const float q0 = b2f((short)(qv & 0xffffu));
  const float q1 = b2f((short)(qv >> 16));
  const float2 bk = *(const float2*)(bias_k + h * 128 + d0);
  float le = q0 * bk.x + q1 * bk.y;
#pragma unroll
  for (int off = 1; off < 64; off <<= 1) le += __shfl_xor(le, off, 64);
  le *= sc;

  const float* pm = pml + (size_t)task * 8;
  float m[4], l[4];
#pragma unroll
  for (int s = 0; s < 4; ++s) { m[s] = pm[s * 2]; l[s] = pm[s * 2 + 1]; }
  float mt = le;
#pragma unroll
  for (int s = 0; s < 4; ++s) mt = fmaxf(mt, m[s]);

  const float pe = expf(le - mt);
  const float2 bv = *(const float2*)(bias_v + h * 128 + d0);
  float acc0 = pe * bv.x, acc1 = pe * bv.y;
  float lt = pe;
#pragma unroll
  for (int s = 0; s < 4; ++s) {
    const float es = expf(m[s] - mt);
    lt += l[s] * es;
    const float2 op = *(const float2*)(po + ((size_t)task * 4 + s) * 128 + d0);
    acc0 += es * op.x;
    acc1 += es * op.y;
  }
  const float inv = 1.f / lt;
  const unsigned int pack =
      ((unsigned int)(unsigned short)f2b(acc1 * inv) << 16) |
      (unsigned short)f2b(acc0 * inv);
  *(unsigned int*)(ctx + ((size_t)(b * 256 + qr)) * D_EMB + h * 128 + d0) = pack;
}

extern "C" void kernel_launch(void* const* d_in, const int* in_sizes, int n_in,
                              void* d_out, int out_size, void* d_ws, size_t ws_size,
                              hipStream_t stream) {
  const float* x   = (const float*)d_in[0];
  const float* xf1 = (const float*)d_in[1];
  const float* xf2 = (const float*)d_in[2];
  const float* L1[12]; const float* L2[12];
  for (int j = 0; j < 12; ++j) { L1[j] = (const float*)d_in[3 + j]; L2[j] = (const float*)d_in[15 + j]; }
  const float* ln_mlp_s = (const float*)d_in[27];
  const float* ln_mlp_o = (const float*)d_in[28];
  const float* w_fc1    = (const float*)d_in[29];
  const float* b_fc1    = (const float*)d_in[30];
  const float* w_fc2    = (const float*)d_in[31];
  const float* b_fc2    = (const float*)d_in[32];
  float* out = (float*)d_out;

  const size_t SZ_XQ  = (size_t)NB * NQ * D_EMB;   // 2M elems
  const size_t SZ_KV  = (size_t)NB * NS * D_EMB;   // 16.8M elems

  float* x1   = (float*)d_ws;
  float* x2   = x1 + SZ_XQ;
  short* h_ln = (short*)(x2 + SZ_XQ);
  short* qh   = h_ln + SZ_XQ;
  short* ctxb = qh + SZ_XQ;
  short* kh   = ctxb + SZ_XQ;
  short* vh   = kh + SZ_KV;                 // holds V^T this version
  short* xfb  = vh + SZ_KV;
  short* Wt   = xfb + SZ_KV;
  short* fc1b = kh;                    // alias: kh dead by MLP time
  float* po   = (float*)Wt;            // attn partials alias (Wt dead during attention)
  float* pml  = (float*)h_ln;          // 512 KB <= h_ln (dead during attention)
  float* pk1  = (float*)kh;            // split-K partials: kh∪vh = 67 MB (dead at proj time)
  float* pk2  = (float*)vh;            // split-K partials: vh∪xfb = 67 MB (dead at MLP time)

  const dim3 blk(256);
  const dim3 blk5(512);
  const dim3 g_kv256((NB * NS / 256) * (D_EMB / 256));  // 256 blocks
  const dim3 g_sk(256);                                 // all split-K gemms
  const dim3 g_cb2(2048);                               // combine 1024x2048
  const dim3 g_cb8(8192);                               // combine 1024x8192
  const dim3 g_tw(D_EMB / 64, D_EMB / 64);
  const dim3 g_tf1(FF / 64, D_EMB / 64);
  const dim3 g_tf2(D_EMB / 64, FF / 64);
  const int  g_cvt = (int)(SZ_KV / 8 / 256);

  // ---- layer 1 ----
  cvt_kernel<<<g_cvt, blk, 0, stream>>>(xf1, xfb, (int)SZ_KV);
  ln_kernel<<<NB * NQ, blk, 0, stream>>>(x, L1[0], L1[1], h_ln);
  transpose_kernel<<<g_tw, blk, 0, stream>>>(L1[2], Wt, D_EMB, D_EMB);
  gemm256_kernel<0,0,8,0><<<g_sk, blk5, 0, stream>>>(h_ln, Wt, nullptr, nullptr, pk1, NB * NQ, D_EMB, D_EMB);
  combine_kernel<8,0,0><<<g_cb2, blk, 0, stream>>>(pk1, L1[3], nullptr, qh, NB * NQ, D_EMB);
  transpose_kernel<<<g_tw, blk, 0, stream>>>(L1[4], Wt, D_EMB, D_EMB);
  gemm256_kernel<0,0,1,0><<<g_kv256, blk5, 0, stream>>>(xfb, Wt, L1[5], nullptr, kh, NB * NS, D_EMB, D_EMB);
  transpose_kernel<<<g_tw, blk, 0, stream>>>(L1[6], Wt, D_EMB, D_EMB);
  gemm256_kernel<0,0,1,1><<<g_kv256, blk5, 0, stream>>>(xfb, Wt, L1[7], nullptr, vh, NB * NS, D_EMB, D_EMB);
  attn_part_kernel<<<1024, blk, 0, stream>>>(qh, kh, vh, po, pml);
  attn_combine_kernel<<<4096, blk, 0, stream>>>(qh, L1[10], L1[11], po, pml, ctxb);
  transpose_kernel<<<g_tw, blk, 0, stream>>>(L1[8], Wt, D_EMB, D_EMB);
  gemm256_kernel<0,0,8,0><<<g_sk, blk5, 0, stream>>>(ctxb, Wt, nullptr, nullptr, pk1, NB * NQ, D_EMB, D_EMB);
  combine_kernel<8,1,1><<<g_cb2, blk, 0, stream>>>(pk1, L1[9], x, x1, NB * NQ, D_EMB);

  // ---- layer 2 ----
  cvt_kernel<<<g_cvt, blk, 0, stream>>>(xf2, xfb, (int)SZ_KV);
  ln_kernel<<<NB * NQ, blk, 0, stream>>>(x1, L2[0], L2[1], h_ln);
  transpose_kernel<<<g_tw, blk, 0, stream>>>(L2[2], Wt, D_EMB, D_EMB);
  gemm256_kernel<0,0,8,0><<<g_sk, blk5, 0, stream>>>(h_ln, Wt, nullptr, nullptr, pk1, NB * NQ, D_EMB, D_EMB);
  combine_kernel<8,0,0><<<g_cb2, blk, 0, stream>>>(pk1, L2[3], nullptr, qh, NB * NQ, D_EMB);
  transpose_kernel<<<g_tw, blk, 0, stream>>>(L2[4], Wt, D_EMB, D_EMB);
  gemm256_kernel<0,0,1,0><<<g_kv256, blk5, 0, stream>>>(xfb, Wt, L2[5], nullptr, kh, NB * NS, D_EMB, D_EMB);
  transpose_kernel<<<g_tw, blk, 0, stream>>>(L2[6], Wt, D_EMB, D_EMB);
  gemm256_kernel<0,0,1,1><<<g_kv256, blk5, 0, stream>>>(xfb, Wt, L2[7], nullptr, vh, NB * NS, D_EMB, D_EMB);
  attn_part_kernel<<<1024, blk, 0, stream>>>(qh, kh, vh, po, pml);
  attn_combine_kernel<<<4096, blk, 0, stream>>>(qh, L2[10], L2[11], po, pml, ctxb);
  transpose_kernel<<<g_tw, blk, 0, stream>>>(L2[8], Wt, D_EMB, D_EMB);
  gemm256_kernel<0,0,8,0><<<g_sk, blk5, 0, stream>>>(ctxb, Wt, nullptr, nullptr, pk1, NB * NQ, D_EMB, D_EMB);
  combine_kernel<8,1,1><<<g_cb2, blk, 0, stream>>>(pk1, L2[9], x1, x2, NB * NQ, D_EMB);

  // ---- MLP ----
  ln_kernel<<<NB * NQ, blk, 0, stream>>>(x2, ln_mlp_s, ln_mlp_o, h_ln);
  transpose_kernel<<<g_tf1, blk, 0, stream>>>(w_fc1, Wt, D_EMB, FF);
  gemm256_kernel<0,0,2,0><<<g_sk, blk5, 0, stream>>>(h_ln, Wt, nullptr, nullptr, pk2, NB * NQ, FF, D_EMB);
  combine_kernel<2,2,0><<<g_cb8, blk, 0, stream>>>(pk2, b_fc1, nullptr, fc1b, NB * NQ, FF);
  transpose_kernel<<<g_tf2, blk, 0, stream>>>(w_fc2, Wt, FF, D_EMB);
  gemm256_kernel<0,0,8,0><<<g_sk, blk5, 0, stream>>>(fc1b, Wt, nullptr, nullptr, pk2, NB * NQ, D_EMB, FF);
  combine_kernel<8,1,1><<<g_cb2, blk, 0, stream>>>(pk2, b_fc2, x2, out, NB * NQ, D_EMB);
}